// Round 2
// baseline (1752.383 us; speedup 1.0000x reference)
//
#include <hip/hip_runtime.h>
#include <math.h>

#define NW 5
#define NS 5
#define BB 25            // NW*NS
#define CD 640
#define HWD 576
#define NP 2880          // NS*HWD
#define KTOP 2304        // int(2880*0.8)
#define EPSF 1e-12f

// ---------------------------------------------------------------------------
// Tiled fp32 GEMM for conv1x1: out[b,o,p] = sum_c W[o,c]*in[b,c,p] + bias[o] (+res)
// tile 128(o) x 128(p), micro 8x8, K-chunk 16. grid (5 ptiles, 5 otiles, 25 b)
// ---------------------------------------------------------------------------
__global__ __launch_bounds__(256) void conv_gemm(
    const float* __restrict__ in, const float* __restrict__ W,
    const float* __restrict__ bias, const float* __restrict__ res,
    float* __restrict__ out)
{
    __shared__ __align__(16) float At[16][128];   // [kk][o]
    __shared__ __align__(16) float Bt[16][128];   // [kk][p]
    const int b  = blockIdx.z;
    const int o0 = blockIdx.y * 128;
    const int p0 = blockIdx.x * 128;
    const int t  = threadIdx.x;
    const int tx = t & 15, ty = t >> 4;

    float acc[8][8];
#pragma unroll
    for (int i = 0; i < 8; ++i)
#pragma unroll
        for (int j = 0; j < 8; ++j) acc[i][j] = 0.f;

    const int arow = t >> 1;          // 0..127 (o within tile)
    const int ac   = (t & 1) * 8;     // 0 or 8 (c within chunk)
    const int brow = t >> 4;          // 0..15  (c within chunk)
    const int bp   = (t & 15) * 8;    // 0..120 (p within tile)
    const bool bvalid = (p0 + bp) < HWD;
    const float* inb = in + (size_t)b * CD * HWD;

    for (int c0 = 0; c0 < CD; c0 += 16) {
        const float* wp = W + (size_t)(o0 + arow) * CD + c0 + ac;
        float4 wa = *(const float4*)wp;
        float4 wb = *(const float4*)(wp + 4);
        float4 ba, bb;
        if (bvalid) {
            const float* ip = inb + (size_t)(c0 + brow) * HWD + p0 + bp;
            ba = *(const float4*)ip; bb = *(const float4*)(ip + 4);
        } else { ba = make_float4(0.f,0.f,0.f,0.f); bb = ba; }
        __syncthreads();
        At[ac+0][arow]=wa.x; At[ac+1][arow]=wa.y; At[ac+2][arow]=wa.z; At[ac+3][arow]=wa.w;
        At[ac+4][arow]=wb.x; At[ac+5][arow]=wb.y; At[ac+6][arow]=wb.z; At[ac+7][arow]=wb.w;
        *(float4*)&Bt[brow][bp]   = ba;
        *(float4*)&Bt[brow][bp+4] = bb;
        __syncthreads();
#pragma unroll
        for (int kk = 0; kk < 16; ++kk) {
            float4 a0 = *(const float4*)&At[kk][ty*8];
            float4 a1 = *(const float4*)&At[kk][ty*8+4];
            float4 b0 = *(const float4*)&Bt[kk][tx*8];
            float4 b1 = *(const float4*)&Bt[kk][tx*8+4];
            float av[8] = {a0.x,a0.y,a0.z,a0.w,a1.x,a1.y,a1.z,a1.w};
            float bv[8] = {b0.x,b0.y,b0.z,b0.w,b1.x,b1.y,b1.z,b1.w};
#pragma unroll
            for (int i = 0; i < 8; ++i)
#pragma unroll
                for (int j = 0; j < 8; ++j)
                    acc[i][j] = fmaf(av[i], bv[j], acc[i][j]);
        }
    }

    if ((p0 + tx*8) < HWD) {
#pragma unroll
        for (int r = 0; r < 8; ++r) {
            int o = o0 + ty*8 + r;
            float bs = bias[o];
            float* op = out + ((size_t)b*CD + o)*HWD + p0 + tx*8;
            float4 v0, v1;
            v0.x=acc[r][0]+bs; v0.y=acc[r][1]+bs; v0.z=acc[r][2]+bs; v0.w=acc[r][3]+bs;
            v1.x=acc[r][4]+bs; v1.y=acc[r][5]+bs; v1.z=acc[r][6]+bs; v1.w=acc[r][7]+bs;
            if (res != nullptr) {
                const float* rp = res + ((size_t)b*CD + o)*HWD + p0 + tx*8;
                float4 r0 = *(const float4*)rp; float4 r1 = *(const float4*)(rp+4);
                v0.x+=r0.x; v0.y+=r0.y; v0.z+=r0.z; v0.w+=r0.w;
                v1.x+=r1.x; v1.y+=r1.y; v1.z+=r1.z; v1.w+=r1.w;
            }
            *(float4*)op = v0; *(float4*)(op+4) = v1;
        }
    }
}

// ---------------------------------------------------------------------------
// QK^T with fused per-(key-shot, p-tile) row max.
// A = xq columns (query i = sq*576+pq), B = xk[n,s]. Writes
// xwp[(z*5+pt)*2880 + i] = max over this p-tile's valid keys of q_i . k
// grid (5 ptiles, 23 itiles, 25 z=n*5+s), block 256
// ---------------------------------------------------------------------------
__global__ __launch_bounds__(256) void qk_max(
    const float* __restrict__ xq, const float* __restrict__ xk,
    float* __restrict__ xwp)
{
    __shared__ __align__(16) float At[16][128];   // [kk][i]
    __shared__ __align__(16) float Bt[16][128];   // [kk][p]
    const int z  = blockIdx.z;
    const int n  = z / 5, s = z % 5;
    const int i0 = blockIdx.y * 128;
    const int pt = blockIdx.x;
    const int p0 = pt * 128;
    const int t  = threadIdx.x;
    const int tx = t & 15, ty = t >> 4;

    float acc[8][8];
#pragma unroll
    for (int i = 0; i < 8; ++i)
#pragma unroll
        for (int j = 0; j < 8; ++j) acc[i][j] = 0.f;

    const int krow = t >> 4;          // kk row for loads
    const int aib  = (t & 15) * 8;    // i offset (8-aligned; 576%8==0 so no straddle)
    const int gi   = i0 + aib;
    const bool avalid = gi < NP;
    const int sq = avalid ? (gi / HWD) : 0;
    const int pq = gi - sq * HWD;
    const float* aqbase = xq + ((size_t)(n*NS + sq) * CD) * HWD + pq;
    const int bpb = (t & 15) * 8;
    const bool bvalid = (p0 + bpb) < HWD;
    const float* bkbase = xk + ((size_t)(n*NS + s) * CD) * HWD + p0 + bpb;

    for (int c0 = 0; c0 < CD; c0 += 16) {
        float4 a0, a1, b0, b1;
        if (avalid) {
            const float* ap = aqbase + (size_t)(c0 + krow) * HWD;
            a0 = *(const float4*)ap; a1 = *(const float4*)(ap + 4);
        } else { a0 = make_float4(0.f,0.f,0.f,0.f); a1 = a0; }
        if (bvalid) {
            const float* bp2 = bkbase + (size_t)(c0 + krow) * HWD;
            b0 = *(const float4*)bp2; b1 = *(const float4*)(bp2 + 4);
        } else { b0 = make_float4(0.f,0.f,0.f,0.f); b1 = b0; }
        __syncthreads();
        *(float4*)&At[krow][aib]   = a0; *(float4*)&At[krow][aib+4] = a1;
        *(float4*)&Bt[krow][bpb]   = b0; *(float4*)&Bt[krow][bpb+4] = b1;
        __syncthreads();
#pragma unroll
        for (int kk = 0; kk < 16; ++kk) {
            float4 A0 = *(const float4*)&At[kk][ty*8];
            float4 A1 = *(const float4*)&At[kk][ty*8+4];
            float4 B0 = *(const float4*)&Bt[kk][tx*8];
            float4 B1 = *(const float4*)&Bt[kk][tx*8+4];
            float av[8] = {A0.x,A0.y,A0.z,A0.w,A1.x,A1.y,A1.z,A1.w};
            float bv[8] = {B0.x,B0.y,B0.z,B0.w,B1.x,B1.y,B1.z,B1.w};
#pragma unroll
            for (int i = 0; i < 8; ++i)
#pragma unroll
                for (int j = 0; j < 8; ++j)
                    acc[i][j] = fmaf(av[i], bv[j], acc[i][j]);
        }
    }

    const bool colsvalid = (p0 + tx*8) < HWD;
#pragma unroll
    for (int r = 0; r < 8; ++r) {
        float m = -INFINITY;
        if (colsvalid) {
#pragma unroll
            for (int j = 0; j < 8; ++j) m = fmaxf(m, acc[r][j]);
        }
#pragma unroll
        for (int off = 1; off < 16; off <<= 1)
            m = fmaxf(m, __shfl_xor(m, off, 64));
        if (tx == 0) {
            int i = i0 + ty*8 + r;
            if (i < NP) xwp[((size_t)z*5 + pt)*NP + i] = m;
        }
    }
}

// x_w[n,i] ~ sum_s max_pt xwp  (scale/softmax dropped: argmax-invariant)
// one block per b=n*5+sq, 576 threads; writes argmax pixel index.
__global__ void xw_argmax(const float* __restrict__ xwp, int* __restrict__ seed_pix)
{
    const int b = blockIdx.x;
    const int n = b / NS, sq = b % NS;
    const int p = threadIdx.x;
    const int i = sq * HWD + p;
    float v = 0.f;
#pragma unroll
    for (int s = 0; s < NS; ++s) {
        float m = -INFINITY;
#pragma unroll
        for (int ptt = 0; ptt < 5; ++ptt)
            m = fmaxf(m, xwp[((size_t)(n*NS+s)*5 + ptt)*NP + i]);
        v += m;
    }
    int lane = p & 63, w = p >> 6;
    float bv = v; int bi = p;
    for (int off = 32; off; off >>= 1) {
        float ov = __shfl_down(bv, off, 64);
        int   oi = __shfl_down(bi, off, 64);
        if (ov > bv || (ov == bv && oi < bi)) { bv = ov; bi = oi; }
    }
    __shared__ float wv[9]; __shared__ int wi[9];
    if (lane == 0) { wv[w] = bv; wi[w] = bi; }
    __syncthreads();
    if (p == 0) {
        float best = wv[0]; int bidx = wi[0];
        for (int k = 1; k < 9; ++k)
            if (wv[k] > best || (wv[k] == best && wi[k] < bidx)) { best = wv[k]; bidx = wi[k]; }
        seed_pix[b] = bidx;
    }
}

// per-pixel inverse L2 norm over channels. grid (9, 25), block 64
__global__ void pixel_norms(const float* __restrict__ src, float* __restrict__ invn)
{
    const int b = blockIdx.y;
    const int p = blockIdx.x * 64 + threadIdx.x;
    const float* sp = src + (size_t)b * CD * HWD + p;
    float acc = 0.f;
    for (int c = 0; c < CD; ++c) { float v = sp[(size_t)c * HWD]; acc = fmaf(v, v, acc); }
    invn[b * HWD + p] = 1.f / fmaxf(sqrtf(acc), EPSF);
}

// seeds[b,c] = norm0 at argmax pixel. grid 25, block 640
__global__ void seeds_gather(const float* __restrict__ x5, const float* __restrict__ invn5,
                             const int* __restrict__ seed_pix, float* __restrict__ seeds)
{
    int b = blockIdx.x, c = threadIdx.x;
    int pix = seed_pix[b];
    seeds[b * CD + c] = x5[((size_t)b * CD + c) * HWD + pix] * invn5[b * HWD + pix];
}

// cor[n,o,p] += sum_k invn5 * sum_{c in chunk} x5*seeds  (atomic over c-chunks)
// grid (4 cchunks, 9 ptiles, 25 no), block 64
__global__ void cor_kernel(const float* __restrict__ x5, const float* __restrict__ invn5,
                           const float* __restrict__ seeds, float* __restrict__ cor)
{
    const int z = blockIdx.z; const int n = z / 5, o = z % 5;
    const int p = blockIdx.y * 64 + threadIdx.x;
    const int c0 = blockIdx.x * 160;
    float acc = 0.f;
    for (int k = 0; k < NS; ++k) {
        const float* xp = x5 + ((size_t)(n*NS+k) * CD) * HWD + p;
        const float* sp = seeds + (size_t)(o*NS+k) * CD;
        float tk = 0.f;
        for (int c = c0; c < c0 + 160; ++c)
            tk = fmaf(xp[(size_t)c * HWD], sp[c], tk);
        acc = fmaf(invn5[(n*NS+k)*HWD + p], tk, acc);
    }
    atomicAdd(&cor[z * HWD + p], acc);
}

// per-(n,o) min/max normalize, in place. grid 25, block 576
__global__ void cor_minmax(float* __restrict__ cor)
{
    int z = blockIdx.x; int p = threadIdx.x;
    float v = cor[z * HWD + p];
    float mn = v, mx = v;
    for (int off = 32; off; off >>= 1) {
        mn = fminf(mn, __shfl_xor(mn, off, 64));
        mx = fmaxf(mx, __shfl_xor(mx, off, 64));
    }
    __shared__ float smn[9], smx[9];
    int lane = p & 63, w = p >> 6;
    if (lane == 0) { smn[w] = mn; smx[w] = mx; }
    __syncthreads();
    __shared__ float fmn, fmx;
    if (p == 0) {
        float a = smn[0], b = smx[0];
        for (int k = 1; k < 9; ++k) { a = fminf(a, smn[k]); b = fmaxf(b, smx[k]); }
        fmn = a; fmx = b;
    }
    __syncthreads();
    cor[z * HWD + p] = (v - fmn) / (fmx - fmn + EPSF);
}

// proto1[n,c] = mean over (o,p) of x5 * cormap. grid (160, 5), block 256 (64p x 4c)
__global__ void proto1_kernel(const float* __restrict__ x5, const float* __restrict__ cor,
                              float* __restrict__ proto1)
{
    int n = blockIdx.y; int ct = blockIdx.x;
    int t = threadIdx.x; int pi = t & 63, cj = t >> 6;
    int c = ct * 4 + cj;
    float acc = 0.f;
    for (int s = 0; s < NS; ++s) {
        const float* xp = x5 + ((size_t)(n*NS+s) * CD + c) * HWD;
        const float* wp = cor + (size_t)(n*NS+s) * HWD;
        for (int p = pi; p < HWD; p += 64) acc = fmaf(xp[p], wp[p], acc);
    }
    for (int off = 32; off; off >>= 1) acc += __shfl_down(acc, off, 64);
    if (pi == 0) proto1[n * CD + c] = acc * (1.f / 2880.f);
}

// out[b,c] = sum_p lf*invn (*mask). grid (160, 25), block 256 (64p x 4c)
__global__ void masked_sum(const float* __restrict__ lf, const float* __restrict__ invn,
                           const float* __restrict__ mask, float* __restrict__ out)
{
    int b = blockIdx.y; int ct = blockIdx.x;
    int t = threadIdx.x; int pi = t & 63, cj = t >> 6;
    int c = ct * 4 + cj;
    const float* xp = lf + ((size_t)b * CD + c) * HWD;
    const float* ip = invn + b * HWD;
    float acc = 0.f;
    if (mask != nullptr) {
        const float* mp = mask + b * HWD;
        for (int p = pi; p < HWD; p += 64) acc = fmaf(xp[p], ip[p] * mp[p], acc);
    } else {
        for (int p = pi; p < HWD; p += 64) acc = fmaf(xp[p], ip[p], acc);
    }
    for (int off = 32; off; off >>= 1) acc += __shfl_down(acc, off, 64);
    if (pi == 0) out[b * CD + c] = acc;
}

__global__ void sway_stot(const float* __restrict__ S_img, float* __restrict__ S_way,
                          float* __restrict__ S_tot)
{
    int c = threadIdx.x;
    float tot = 0.f;
    for (int nn = 0; nn < NW; ++nn) {
        float w = 0.f;
        for (int s = 0; s < NS; ++s) w += S_img[(nn*NS+s)*CD + c];
        S_way[nn*CD + c] = w; tot += w;
    }
    S_tot[c] = tot;
}

// cds = sigmoid(d_intra/d_inter). grid (9, 25), block 64
__global__ void cds_kernel(const float* __restrict__ lf, const float* __restrict__ invn,
                           const float* __restrict__ S_way, const float* __restrict__ S_img,
                           const float* __restrict__ S_tot, float* __restrict__ cds)
{
    int b = blockIdx.y; int p = blockIdx.x * 64 + threadIdx.x;
    int n = b / NS;
    const float* xp = lf + (size_t)b * CD * HWD + p;
    const float* wv = S_way + n * CD;
    const float* iv = S_img + b * CD;
    float dw = 0.f, di = 0.f, dt = 0.f, sq = 0.f;
    for (int c = 0; c < CD; ++c) {
        float v = xp[(size_t)c * HWD];
        dw = fmaf(v, wv[c], dw);
        di = fmaf(v, iv[c], di);
        dt = fmaf(v, S_tot[c], dt);
        sq = fmaf(v, v, sq);
    }
    float in1 = invn[b * HWD + p];
    float d_intra = (in1 * dw - in1 * in1 * sq) * (1.f / 2880.f);
    float d_inter = (in1 * dt - in1 * di) * (1.f / 14400.f);
    float r = d_intra / d_inter;
    cds[n * NP + (b % NS) * HWD + p] = 1.f / (1.f + expf(-r));
}

// exact top-2304-of-2880 per way via 32-bit radix select on order-mapped uints;
// jax tie-break (lowest index first). grid 5, block 576
__global__ void topk_kernel(const float* __restrict__ cds, float* __restrict__ sel)
{
    __shared__ unsigned int u[NP];
    __shared__ int red[16];
    __shared__ int bcast;
    __shared__ int scanbuf[576];
    const int n = blockIdx.x, t = threadIdx.x;
    for (int j = t; j < NP; j += 576) {
        unsigned int x = __float_as_uint(cds[n * NP + j]);
        u[j] = (x & 0x80000000u) ? ~x : (x | 0x80000000u);
    }
    __syncthreads();
    const int j0 = t * 5;
    const int lane = t & 63, w = t >> 6;
    int kk = KTOP;
    unsigned int prefix = 0;
    for (int bit = 31; bit >= 0; --bit) {
        unsigned int want = (prefix >> bit) | 1u;
        int cnt = 0;
#pragma unroll
        for (int e = 0; e < 5; ++e) if ((u[j0+e] >> bit) == want) cnt++;
        for (int off = 32; off; off >>= 1) cnt += __shfl_down(cnt, off, 64);
        if (lane == 0) red[w] = cnt;
        __syncthreads();
        if (t == 0) { int s2 = 0; for (int q = 0; q < 9; ++q) s2 += red[q]; bcast = s2; }
        __syncthreads();
        int c1 = bcast;
        if (c1 >= kk) prefix |= (1u << bit);
        else kk -= c1;
        __syncthreads();
    }
    const unsigned int T = prefix;
    int cg = 0, ce = 0;
#pragma unroll
    for (int e = 0; e < 5; ++e) {
        unsigned v = u[j0+e];
        if (v > T) cg++; else if (v == T) ce++;
    }
    int r1 = cg;
    for (int off = 32; off; off >>= 1) r1 += __shfl_down(r1, off, 64);
    if (lane == 0) red[w] = r1;
    __syncthreads();
    if (t == 0) { int s2 = 0; for (int q = 0; q < 9; ++q) s2 += red[q]; bcast = s2; }
    __syncthreads();
    const int need = KTOP - bcast;
    scanbuf[t] = ce;
    __syncthreads();
    for (int off = 1; off < 576; off <<= 1) {
        int v2 = (t >= off) ? scanbuf[t - off] : 0;
        __syncthreads();
        scanbuf[t] += v2;
        __syncthreads();
    }
    int excl = scanbuf[t] - ce;
    int eidx = 0;
#pragma unroll
    for (int e = 0; e < 5; ++e) {
        int j = j0 + e;
        unsigned v = u[j];
        float s = 0.f;
        if (v > T) s = 1.f;
        else if (v == T) { if (excl + eidx < need) s = 1.f; eidx++; }
        int sh = j / HWD;
        sel[(n*NS + sh) * HWD + (j - sh*HWD)] = s;
    }
}

// contrastive_loss = exp(5*(A-C)/(B-A)); A=sum_n ||Wsum_n||^2, B=||Tsum||^2, C=sum_b ||Sm_b||^2
__global__ void closs_kernel(const float* __restrict__ Sm, float* __restrict__ out)
{
    int c = threadIdx.x;
    double A = 0.0, Bv = 0.0, Cv = 0.0;
    float tot = 0.f;
    for (int nn = 0; nn < NW; ++nn) {
        float ws = 0.f;
        for (int s = 0; s < NS; ++s) {
            float v = Sm[(nn*NS+s)*CD + c];
            ws += v; Cv += (double)v * v;
        }
        tot += ws; A += (double)ws * ws;
    }
    Bv = (double)tot * tot;
    int lane = c & 63, w = c >> 6;
    for (int off = 32; off; off >>= 1) {
        A  += __shfl_down(A,  off, 64);
        Bv += __shfl_down(Bv, off, 64);
        Cv += __shfl_down(Cv, off, 64);
    }
    __shared__ double sa[10], sb[10], sc[10];
    if (lane == 0) { sa[w] = A; sb[w] = Bv; sc[w] = Cv; }
    __syncthreads();
    if (c == 0) {
        double a = 0, b2 = 0, cc = 0;
        for (int q = 0; q < 10; ++q) { a += sa[q]; b2 += sb[q]; cc += sc[q]; }
        out[0] = (float)exp(5.0 * (a - cc) / (b2 - a));
    }
}

// per-pixel sum_c exp(X*gpa); accumulate pos/neg totals. grid (9, 25), block 64
__global__ void ctc_kernel(const float* __restrict__ lf, const float* __restrict__ invn,
                           const float* __restrict__ proto1, const float* __restrict__ sel,
                           float* __restrict__ scal)
{
    int b = blockIdx.y; int p = blockIdx.x * 64 + threadIdx.x;
    int n = b / NS;
    const float* xp = lf + (size_t)b * CD * HWD + p;
    const float* pr = proto1 + n * CD;
    float in1 = invn[b * HWD + p];
    float acc = 0.f;
    for (int c = 0; c < CD; ++c) acc += expf(xp[(size_t)c * HWD] * in1 * pr[c]);
    float s = sel[b * HWD + p];
    float pv = (s > 0.5f) ? acc : 640.f;
    float nv = (s > 0.5f) ? 640.f : acc;
    for (int off = 32; off; off >>= 1) {
        pv += __shfl_down(pv, off, 64);
        nv += __shfl_down(nv, off, 64);
    }
    if ((threadIdx.x & 63) == 0) { atomicAdd(&scal[0], pv); atomicAdd(&scal[1], nv); }
}

__global__ void finalize_kernel(const float* __restrict__ scal, float* __restrict__ out)
{
    if (threadIdx.x == 0) out[1] = -(logf(scal[0]) - logf(scal[1]));
}

// pos_index broadcast write: out2[b,c,p] = sel[b,p]. 9000 blocks x 256, 1 float4-group each
__global__ void posindex_kernel(const float* __restrict__ sel, float* __restrict__ out2)
{
    int idx = blockIdx.x * 256 + threadIdx.x;      // 25*640*144 = 2,304,000 groups
    int row = idx / 144;                            // b*640 + c
    int f4  = idx - row * 144;
    int b   = row / CD;
    const float* sp = sel + b * HWD + f4 * 4;
    float* op = out2 + (size_t)row * HWD + f4 * 4;
    float2 v0 = make_float2(sp[0], sp[1]);
    float2 v1 = make_float2(sp[2], sp[3]);
    *(float2*)op = v0; *(float2*)(op + 2) = v1;
}

__global__ void init_zero(float* __restrict__ cor, float* __restrict__ scal)
{
    int i = blockIdx.x * 256 + threadIdx.x;
    if (i < BB * HWD) cor[i] = 0.f;
    if (i < 2) scal[i] = 0.f;
}

extern "C" void kernel_launch(void* const* d_in, const int* in_sizes, int n_in,
                              void* d_out, int out_size, void* d_ws, size_t ws_size,
                              hipStream_t stream) {
    const float* lf = (const float*)d_in[0];
    const float* Wc = (const float*)d_in[1];
    const float* bc = (const float*)d_in[2];
    const float* Wq = (const float*)d_in[3];
    const float* bq = (const float*)d_in[4];
    const float* Wk = (const float*)d_in[5];
    const float* bk = (const float*)d_in[6];
    float* out = (float*)d_out;
    float* ws = (float*)d_ws;

    // Workspace layout. If ws is too small for three 36.9MB feature buffers,
    // alias buf2 (xk) onto the pos_index output region (out+2, exactly 9,216,000
    // floats): xk's last read (qk_max) precedes posindex_kernel, which overwrites
    // it last. ws_size is constant across calls -> graph-capture safe.
    const size_t FEAT = 9216000;
    size_t off = 0;
    auto alloc = [&](size_t nf) { float* p = ws + off; off += (nf + 3) & ~(size_t)3; return p; };
    float* buf0 = alloc(FEAT);        // x5a, later xq
    float* buf1 = alloc(FEAT);        // x5
    const size_t small_need = 360000 + 32 + 16000 + 14400*5 + 3200*2 + 640 + 16000*2 + 8 + 64;
    bool alias_buf2 = (ws_size / sizeof(float)) < (3 * (FEAT + 4) + small_need);
    float* buf2 = alias_buf2 ? (out + 2) : alloc(FEAT);   // xk
    float* xwp    = alloc(360000);
    int*   seedpx = (int*)alloc(32);
    float* seeds  = alloc(16000);
    float* invn5  = alloc(14400);
    float* invnl  = alloc(14400);
    float* cor    = alloc(14400);
    float* proto1 = alloc(3200);
    float* S_img  = alloc(16000);
    float* S_way  = alloc(3200);
    float* S_tot  = alloc(640);
    float* cds    = alloc(14400);
    float* sel    = alloc(14400);
    float* Sm     = alloc(16000);
    float* scal   = alloc(8);

    init_zero<<<57, 256, 0, stream>>>(cor, scal);

    // attention conv chain
    conv_gemm<<<dim3(5,5,25), 256, 0, stream>>>(lf,   Wc, bc, lf,      buf0); // x5a = Wc*x+bc+x
    conv_gemm<<<dim3(5,5,25), 256, 0, stream>>>(buf0, Wq, bq, nullptr, buf1); // x5  = Wq*x5a+bq
    conv_gemm<<<dim3(5,5,25), 256, 0, stream>>>(buf1, Wq, bq, nullptr, buf0); // xq  = Wq*x5+bq
    conv_gemm<<<dim3(5,5,25), 256, 0, stream>>>(buf1, Wk, bk, nullptr, buf2); // xk  = Wk*x5+bk

    qk_max<<<dim3(5,23,25), 256, 0, stream>>>(buf0, buf2, xwp);
    pixel_norms<<<dim3(9,25), 64, 0, stream>>>(buf1, invn5);
    pixel_norms<<<dim3(9,25), 64, 0, stream>>>(lf, invnl);
    xw_argmax<<<25, 576, 0, stream>>>(xwp, seedpx);
    seeds_gather<<<25, 640, 0, stream>>>(buf1, invn5, seedpx, seeds);
    cor_kernel<<<dim3(4,9,25), 64, 0, stream>>>(buf1, invn5, seeds, cor);
    cor_minmax<<<25, 576, 0, stream>>>(cor);
    proto1_kernel<<<dim3(160,5), 256, 0, stream>>>(buf1, cor, proto1);

    // cdsnet
    masked_sum<<<dim3(160,25), 256, 0, stream>>>(lf, invnl, nullptr, S_img);
    sway_stot<<<1, 640, 0, stream>>>(S_img, S_way, S_tot);
    cds_kernel<<<dim3(9,25), 64, 0, stream>>>(lf, invnl, S_way, S_img, S_tot, cds);
    topk_kernel<<<5, 576, 0, stream>>>(cds, sel);
    masked_sum<<<dim3(160,25), 256, 0, stream>>>(lf, invnl, sel, Sm);
    closs_kernel<<<1, 640, 0, stream>>>(Sm, out);           // out[0]

    // ctc
    ctc_kernel<<<dim3(9,25), 64, 0, stream>>>(lf, invnl, proto1, sel, scal);
    finalize_kernel<<<1, 64, 0, stream>>>(scal, out);        // out[1]

    // pos_index
    posindex_kernel<<<9000, 256, 0, stream>>>(sel, out + 2);
}

// Round 3
// 1711.532 us; speedup vs baseline: 1.0239x; 1.0239x over previous
//
#include <hip/hip_runtime.h>
#include <math.h>

#define NW 5
#define NS 5
#define BB 25            // NW*NS
#define CD 640
#define HWD 576
#define NP 2880          // NS*HWD
#define KTOP 2304        // int(2880*0.8)
#define EPSF 1e-12f

typedef __attribute__((ext_vector_type(8))) short short8;   // 8 bf16 (4 VGPRs)
typedef __attribute__((ext_vector_type(4))) float f32x4;

__device__ inline unsigned short f2bf(float x) {            // RNE float->bf16
    unsigned u = __float_as_uint(x);
    return (unsigned short)((u + 0x7fffu + ((u >> 16) & 1u)) >> 16);
}
__device__ inline float bf2f(unsigned short h) { return __uint_as_float(((unsigned)h) << 16); }

// ---------------------------------------------------------------------------
// Tiled fp32 GEMM for conv1x1: out[b,o,p] = sum_c W[o,c]*in[b,c,p] + bias[o] (+res)
// tile 128(o) x 128(p), micro 8x8, K-chunk 16. grid (5 ptiles, 5 otiles, 25 b)
// ---------------------------------------------------------------------------
__global__ __launch_bounds__(256) void conv_gemm(
    const float* __restrict__ in, const float* __restrict__ W,
    const float* __restrict__ bias, const float* __restrict__ res,
    float* __restrict__ out)
{
    __shared__ __align__(16) float At[16][128];   // [kk][o]
    __shared__ __align__(16) float Bt[16][128];   // [kk][p]
    const int b  = blockIdx.z;
    const int o0 = blockIdx.y * 128;
    const int p0 = blockIdx.x * 128;
    const int t  = threadIdx.x;
    const int tx = t & 15, ty = t >> 4;

    float acc[8][8];
#pragma unroll
    for (int i = 0; i < 8; ++i)
#pragma unroll
        for (int j = 0; j < 8; ++j) acc[i][j] = 0.f;

    const int arow = t >> 1;
    const int ac   = (t & 1) * 8;
    const int brow = t >> 4;
    const int bp   = (t & 15) * 8;
    const bool bvalid = (p0 + bp) < HWD;
    const float* inb = in + (size_t)b * CD * HWD;

    for (int c0 = 0; c0 < CD; c0 += 16) {
        const float* wp = W + (size_t)(o0 + arow) * CD + c0 + ac;
        float4 wa = *(const float4*)wp;
        float4 wb = *(const float4*)(wp + 4);
        float4 ba, bb;
        if (bvalid) {
            const float* ip = inb + (size_t)(c0 + brow) * HWD + p0 + bp;
            ba = *(const float4*)ip; bb = *(const float4*)(ip + 4);
        } else { ba = make_float4(0.f,0.f,0.f,0.f); bb = ba; }
        __syncthreads();
        At[ac+0][arow]=wa.x; At[ac+1][arow]=wa.y; At[ac+2][arow]=wa.z; At[ac+3][arow]=wa.w;
        At[ac+4][arow]=wb.x; At[ac+5][arow]=wb.y; At[ac+6][arow]=wb.z; At[ac+7][arow]=wb.w;
        *(float4*)&Bt[brow][bp]   = ba;
        *(float4*)&Bt[brow][bp+4] = bb;
        __syncthreads();
#pragma unroll
        for (int kk = 0; kk < 16; ++kk) {
            float4 a0 = *(const float4*)&At[kk][ty*8];
            float4 a1 = *(const float4*)&At[kk][ty*8+4];
            float4 b0 = *(const float4*)&Bt[kk][tx*8];
            float4 b1 = *(const float4*)&Bt[kk][tx*8+4];
            float av[8] = {a0.x,a0.y,a0.z,a0.w,a1.x,a1.y,a1.z,a1.w};
            float bv[8] = {b0.x,b0.y,b0.z,b0.w,b1.x,b1.y,b1.z,b1.w};
#pragma unroll
            for (int i = 0; i < 8; ++i)
#pragma unroll
                for (int j = 0; j < 8; ++j)
                    acc[i][j] = fmaf(av[i], bv[j], acc[i][j]);
        }
    }

    if ((p0 + tx*8) < HWD) {
#pragma unroll
        for (int r = 0; r < 8; ++r) {
            int o = o0 + ty*8 + r;
            float bs = bias[o];
            float* op = out + ((size_t)b*CD + o)*HWD + p0 + tx*8;
            float4 v0, v1;
            v0.x=acc[r][0]+bs; v0.y=acc[r][1]+bs; v0.z=acc[r][2]+bs; v0.w=acc[r][3]+bs;
            v1.x=acc[r][4]+bs; v1.y=acc[r][5]+bs; v1.z=acc[r][6]+bs; v1.w=acc[r][7]+bs;
            if (res != nullptr) {
                const float* rp = res + ((size_t)b*CD + o)*HWD + p0 + tx*8;
                float4 r0 = *(const float4*)rp; float4 r1 = *(const float4*)(rp+4);
                v0.x+=r0.x; v0.y+=r0.y; v0.z+=r0.z; v0.w+=r0.w;
                v1.x+=r1.x; v1.y+=r1.y; v1.z+=r1.z; v1.w+=r1.w;
            }
            *(float4*)op = v0; *(float4*)(op+4) = v1;
        }
    }
}

// M2[o][c] = sum_m Wq[m][o]*Wk[m][c]   (Wq^T Wk). grid (10,10), block 256, 4x4/thread
__global__ __launch_bounds__(256) void mtm_kernel(
    const float* __restrict__ Wq, const float* __restrict__ Wk, float* __restrict__ M2)
{
    const int o0 = blockIdx.y*64 + (threadIdx.x >> 4)*4;
    const int j0 = blockIdx.x*64 + (threadIdx.x & 15)*4;
    float acc[4][4];
#pragma unroll
    for (int r = 0; r < 4; ++r)
#pragma unroll
        for (int s = 0; s < 4; ++s) acc[r][s] = 0.f;
    for (int c = 0; c < CD; ++c) {
        float4 a = *(const float4*)&Wq[(size_t)c*CD + o0];
        float4 b2 = *(const float4*)&Wk[(size_t)c*CD + j0];
        float av[4] = {a.x,a.y,a.z,a.w}, bv[4] = {b2.x,b2.y,b2.z,b2.w};
#pragma unroll
        for (int r = 0; r < 4; ++r)
#pragma unroll
            for (int s = 0; s < 4; ++s) acc[r][s] = fmaf(av[r], bv[s], acc[r][s]);
    }
#pragma unroll
    for (int r = 0; r < 4; ++r)
#pragma unroll
        for (int s = 0; s < 4; ++s) M2[(size_t)(o0+r)*CD + j0 + s] = acc[r][s];
}

// wqtbk[o] = sum_m Wq[m][o]*bk[m];  bqwk[j] = sum_m bq[m]*Wk[m][j];  sbb = bq.bk
__global__ void biasvec_kernel(const float* __restrict__ Wq, const float* __restrict__ Wk,
                               const float* __restrict__ bq, const float* __restrict__ bk,
                               float* __restrict__ wqtbk, float* __restrict__ bqwk,
                               float* __restrict__ sbb)
{
    int c = threadIdx.x;
    float s1 = 0.f, s2 = 0.f;
    for (int m = 0; m < CD; ++m) {
        s1 = fmaf(Wq[(size_t)m*CD + c], bk[m], s1);
        s2 = fmaf(bq[m], Wk[(size_t)m*CD + c], s2);
    }
    wqtbk[c] = s1; bqwk[c] = s2;
    if (c == 0) { float s3 = 0.f; for (int m = 0; m < CD; ++m) s3 = fmaf(bq[m], bk[m], s3); sbb[0] = s3; }
}

// rvec[b*576+p] = sum_c x5[b][c][p]*bqwk[c] + sbb. grid (9,25), block 256
__global__ __launch_bounds__(256) void rvec_kernel(const float* __restrict__ x5,
                                                   const float* __restrict__ bqwk,
                                                   const float* __restrict__ sbb,
                                                   float* __restrict__ rvec)
{
    const int b = blockIdx.y, t = threadIdx.x;
    const int p = blockIdx.x*64 + (t >> 2);
    const int cb = (t & 3) * 160;
    const float* xp = x5 + (size_t)b*CD*HWD + p + (size_t)cb*HWD;
    const float* wv = bqwk + cb;
    float a = 0.f;
    for (int c = 0; c < 160; ++c) a = fmaf(xp[(size_t)c*HWD], wv[c], a);
    a += __shfl_xor(a, 1, 64); a += __shfl_xor(a, 2, 64);
    if ((t & 3) == 0) rvec[b*HWD + p] = a + sbb[0];
}

// ---------------------------------------------------------------------------
// Transpose + bf16 hi/lo split: in [b][c][p] fp32 -> Oh/Ol rows [b*576+p][c].
// grid (90 = 10 ctiles x 9 ptiles, 25 b), block 256, 64x64 tiles.
// ---------------------------------------------------------------------------
__global__ __launch_bounds__(256) void convert_t(const float* __restrict__ in,
        unsigned short* __restrict__ Oh, unsigned short* __restrict__ Ol)
{
    __shared__ float tile[64][65];
    const int b  = blockIdx.y;
    const int c0 = (blockIdx.x / 9) * 64;
    const int p0 = (blockIdx.x % 9) * 64;
    const int t  = threadIdx.x;
    const float* src = in + (size_t)b * CD * HWD;
#pragma unroll
    for (int it = 0; it < 4; ++it) {
        int cl = (t >> 4) + 16*it, pl = (t & 15) * 4;
        float4 v = *(const float4*)&src[(size_t)(c0+cl)*HWD + p0 + pl];
        tile[cl][pl] = v.x; tile[cl][pl+1] = v.y; tile[cl][pl+2] = v.z; tile[cl][pl+3] = v.w;
    }
    __syncthreads();
#pragma unroll
    for (int it = 0; it < 4; ++it) {
        int pl = (t >> 4) + 16*it, clb = (t & 15) * 4;
        ushort4 hv, lv;
        float x0 = tile[clb+0][pl], x1 = tile[clb+1][pl], x2 = tile[clb+2][pl], x3 = tile[clb+3][pl];
        hv.x = f2bf(x0); hv.y = f2bf(x1); hv.z = f2bf(x2); hv.w = f2bf(x3);
        lv.x = f2bf(x0 - bf2f(hv.x)); lv.y = f2bf(x1 - bf2f(hv.y));
        lv.z = f2bf(x2 - bf2f(hv.z)); lv.w = f2bf(x3 - bf2f(hv.w));
        size_t o = (size_t)(b*HWD + p0 + pl) * CD + c0 + clb;
        *(ushort4*)&Oh[o] = hv;
        *(ushort4*)&Ol[o] = lv;
    }
}

// ---------------------------------------------------------------------------
// S = Q . K^T via split-bf16 MFMA (3-term: hh + hl + lh), fused per-key-shot max.
// Q rows [n*2880 + i][c], K rows [n*2880 + j][c], j tiled 192 within one shot.
// Adds rank-1 bias rvec[j] before the max. grid (15 = 5shot x 3jt, 30 itiles, 5 n).
// ---------------------------------------------------------------------------
__global__ __launch_bounds__(256) void qk_mfma(
    const unsigned short* __restrict__ Qh, const unsigned short* __restrict__ Ql,
    const unsigned short* __restrict__ Kh, const unsigned short* __restrict__ Kl,
    const float* __restrict__ rvec, float* __restrict__ xwp)
{
    // LDS: Ah[96][32] | Al[96][32] | Bh[192][32] | Bl[192][32]  bf16, pitch 32 (=64B)
    __shared__ __align__(16) unsigned short lds[18432];     // 36 KB
    const int n    = blockIdx.z;
    const int i0   = blockIdx.y * 96;
    const int shot = blockIdx.x / 3;
    const int jt   = blockIdx.x % 3;
    const int t    = threadIdx.x;
    const int w    = t >> 6, lane = t & 63;
    const int ihalf = (w & 1) * 48;
    const int jhalf = (w >> 1) * 96;

    const size_t qbase = (size_t)(n*NP + i0) * CD;
    const size_t kbase = (size_t)(n*NP + shot*HWD + jt*192) * CD;

    f32x4 acc[3][6];
#pragma unroll
    for (int f = 0; f < 3; ++f)
#pragma unroll
        for (int g = 0; g < 6; ++g) acc[f][g] = (f32x4){0.f,0.f,0.f,0.f};

    for (int c0 = 0; c0 < CD; c0 += 32) {
        float4 tmp[9];
#pragma unroll
        for (int e = 0; e < 9; ++e) {
            int seg = t + e*256;
            const unsigned short* src;
            if (seg < 384)        { int x = seg;        src = Qh + qbase + (size_t)(x>>2)*CD + c0 + (x&3)*8; }
            else if (seg < 768)   { int x = seg - 384;  src = Ql + qbase + (size_t)(x>>2)*CD + c0 + (x&3)*8; }
            else if (seg < 1536)  { int x = seg - 768;  src = Kh + kbase + (size_t)(x>>2)*CD + c0 + (x&3)*8; }
            else                  { int x = seg - 1536; src = Kl + kbase + (size_t)(x>>2)*CD + c0 + (x&3)*8; }
            tmp[e] = *(const float4*)src;
        }
        __syncthreads();
#pragma unroll
        for (int e = 0; e < 9; ++e) { int seg = t + e*256; *(float4*)&lds[(size_t)seg*8] = tmp[e]; }
        __syncthreads();

        const int chunk = (lane >> 4) * 8;
        short8 afh[3], afl[3];
#pragma unroll
        for (int f = 0; f < 3; ++f) {
            int row = ihalf + f*16 + (lane & 15);
            afh[f] = *(const short8*)&lds[row*32 + chunk];
            afl[f] = *(const short8*)&lds[3072 + row*32 + chunk];
        }
#pragma unroll
        for (int g = 0; g < 6; ++g) {
            int row = jhalf + g*16 + (lane & 15);
            short8 bfh = *(const short8*)&lds[6144  + row*32 + chunk];
            short8 bfl = *(const short8*)&lds[12288 + row*32 + chunk];
#pragma unroll
            for (int f = 0; f < 3; ++f) {
                acc[f][g] = __builtin_amdgcn_mfma_f32_16x16x32_bf16(afh[f], bfh, acc[f][g], 0, 0, 0);
                acc[f][g] = __builtin_amdgcn_mfma_f32_16x16x32_bf16(afh[f], bfl, acc[f][g], 0, 0, 0);
                acc[f][g] = __builtin_amdgcn_mfma_f32_16x16x32_bf16(afl[f], bfh, acc[f][g], 0, 0, 0);
            }
        }
    }

    // epilogue: add rvec[j], max over this block's 192 keys, per query row
    float rv[6];
    {
        int jg0 = n*NP + shot*HWD + jt*192 + jhalf + (lane & 15);
#pragma unroll
        for (int g = 0; g < 6; ++g) rv[g] = rvec[jg0 + g*16];
    }
    __syncthreads();
    float* smax = (float*)lds;      // [96][2]
#pragma unroll
    for (int f = 0; f < 3; ++f) {
#pragma unroll
        for (int r = 0; r < 4; ++r) {
            float m = -INFINITY;
#pragma unroll
            for (int g = 0; g < 6; ++g) m = fmaxf(m, acc[f][g][r] + rv[g]);
#pragma unroll
            for (int off = 1; off < 16; off <<= 1) m = fmaxf(m, __shfl_xor(m, off, 64));
            if ((lane & 15) == 0) smax[(ihalf + f*16 + (lane >> 4)*4 + r)*2 + (w >> 1)] = m;
        }
    }
    __syncthreads();
    if (t < 96) {
        float m = fmaxf(smax[t*2], smax[t*2 + 1]);
        xwp[(((size_t)n*5 + shot)*3 + jt)*NP + i0 + t] = m;
    }
}

// x_w[n,i] ~ sum_s max_jt xwp  (scale/softmax dropped: argmax-invariant)
__global__ void xw_argmax(const float* __restrict__ xwp, int* __restrict__ seed_pix)
{
    const int b = blockIdx.x;
    const int n = b / NS, sq = b % NS;
    const int p = threadIdx.x;
    const int i = sq * HWD + p;
    float v = 0.f;
#pragma unroll
    for (int s = 0; s < NS; ++s) {
        float m = -INFINITY;
#pragma unroll
        for (int tt = 0; tt < 3; ++tt)
            m = fmaxf(m, xwp[(((size_t)(n*NS+s))*3 + tt)*NP + i]);
        v += m;
    }
    int lane = p & 63, w = p >> 6;
    float bv = v; int bi = p;
    for (int off = 32; off; off >>= 1) {
        float ov = __shfl_down(bv, off, 64);
        int   oi = __shfl_down(bi, off, 64);
        if (ov > bv || (ov == bv && oi < bi)) { bv = ov; bi = oi; }
    }
    __shared__ float wv[9]; __shared__ int wi[9];
    if (lane == 0) { wv[w] = bv; wi[w] = bi; }
    __syncthreads();
    if (p == 0) {
        float best = wv[0]; int bidx = wi[0];
        for (int k = 1; k < 9; ++k)
            if (wv[k] > best || (wv[k] == best && wi[k] < bidx)) { best = wv[k]; bidx = wi[k]; }
        seed_pix[b] = bidx;
    }
}

// per-pixel inverse L2 norm. grid (9,25), block 256 (64 pixels x 4 c-chunks)
__global__ __launch_bounds__(256) void pixel_norms(const float* __restrict__ src, float* __restrict__ invn)
{
    const int b = blockIdx.y, t = threadIdx.x;
    const int p = blockIdx.x*64 + (t >> 2);
    const int cb = (t & 3) * 160;
    const float* sp = src + (size_t)b*CD*HWD + p + (size_t)cb*HWD;
    float a = 0.f;
    for (int c = 0; c < 160; ++c) { float v = sp[(size_t)c*HWD]; a = fmaf(v, v, a); }
    a += __shfl_xor(a, 1, 64); a += __shfl_xor(a, 2, 64);
    if ((t & 3) == 0) invn[b*HWD + p] = 1.f / fmaxf(sqrtf(a), EPSF);
}

__global__ void seeds_gather(const float* __restrict__ x5, const float* __restrict__ invn5,
                             const int* __restrict__ seed_pix, float* __restrict__ seeds)
{
    int b = blockIdx.x, c = threadIdx.x;
    int pix = seed_pix[b];
    seeds[b * CD + c] = x5[((size_t)b * CD + c) * HWD + pix] * invn5[b * HWD + pix];
}

// cor[n,o,p] += invn5 * sum_c x5*seeds, x5 read once for all 5 o. grid (9, 25 b=(n,k))
__global__ __launch_bounds__(256) void cor_v2(const float* __restrict__ x5, const float* __restrict__ invn5,
                           const float* __restrict__ seeds, float* __restrict__ cor)
{
    const int b = blockIdx.y;
    const int n = b / NS, k = b % NS;
    const int t = threadIdx.x;
    const int p = blockIdx.x*64 + (t >> 2);
    const int cb = (t & 3) * 160;
    const float* xp = x5 + (size_t)b*CD*HWD + p;
    float a[5] = {0.f,0.f,0.f,0.f,0.f};
    for (int c = 0; c < 160; ++c) {
        float v = xp[(size_t)(cb + c)*HWD];
#pragma unroll
        for (int o = 0; o < 5; ++o)
            a[o] = fmaf(v, seeds[(o*NS + k)*CD + cb + c], a[o]);
    }
    float in1 = invn5[b*HWD + p];
#pragma unroll
    for (int o = 0; o < 5; ++o) {
        float s = a[o];
        s += __shfl_xor(s, 1, 64); s += __shfl_xor(s, 2, 64);
        if ((t & 3) == 0) atomicAdd(&cor[(n*5 + o)*HWD + p], in1 * s);
    }
}

__global__ void cor_minmax(float* __restrict__ cor)
{
    int z = blockIdx.x; int p = threadIdx.x;
    float v = cor[z * HWD + p];
    float mn = v, mx = v;
    for (int off = 32; off; off >>= 1) {
        mn = fminf(mn, __shfl_xor(mn, off, 64));
        mx = fmaxf(mx, __shfl_xor(mx, off, 64));
    }
    __shared__ float smn[9], smx[9];
    int lane = p & 63, w = p >> 6;
    if (lane == 0) { smn[w] = mn; smx[w] = mx; }
    __syncthreads();
    __shared__ float fmn, fmx;
    if (p == 0) {
        float a = smn[0], b = smx[0];
        for (int k = 1; k < 9; ++k) { a = fminf(a, smn[k]); b = fmaxf(b, smx[k]); }
        fmn = a; fmx = b;
    }
    __syncthreads();
    cor[z * HWD + p] = (v - fmn) / (fmx - fmn + EPSF);
}

__global__ void proto1_kernel(const float* __restrict__ x5, const float* __restrict__ cor,
                              float* __restrict__ proto1)
{
    int n = blockIdx.y; int ct = blockIdx.x;
    int t = threadIdx.x; int pi = t & 63, cj = t >> 6;
    int c = ct * 4 + cj;
    float acc = 0.f;
    for (int s = 0; s < NS; ++s) {
        const float* xp = x5 + ((size_t)(n*NS+s) * CD + c) * HWD;
        const float* wp = cor + (size_t)(n*NS+s) * HWD;
        for (int p = pi; p < HWD; p += 64) acc = fmaf(xp[p], wp[p], acc);
    }
    for (int off = 32; off; off >>= 1) acc += __shfl_down(acc, off, 64);
    if (pi == 0) proto1[n * CD + c] = acc * (1.f / 2880.f);
}

__global__ void masked_sum(const float* __restrict__ lf, const float* __restrict__ invn,
                           const float* __restrict__ mask, float* __restrict__ out)
{
    int b = blockIdx.y; int ct = blockIdx.x;
    int t = threadIdx.x; int pi = t & 63, cj = t >> 6;
    int c = ct * 4 + cj;
    const float* xp = lf + ((size_t)b * CD + c) * HWD;
    const float* ip = invn + b * HWD;
    float acc = 0.f;
    if (mask != nullptr) {
        const float* mp = mask + b * HWD;
        for (int p = pi; p < HWD; p += 64) acc = fmaf(xp[p], ip[p] * mp[p], acc);
    } else {
        for (int p = pi; p < HWD; p += 64) acc = fmaf(xp[p], ip[p], acc);
    }
    for (int off = 32; off; off >>= 1) acc += __shfl_down(acc, off, 64);
    if (pi == 0) out[b * CD + c] = acc;
}

__global__ void sway_stot(const float* __restrict__ S_img, float* __restrict__ S_way,
                          float* __restrict__ S_tot)
{
    int c = threadIdx.x;
    float tot = 0.f;
    for (int nn = 0; nn < NW; ++nn) {
        float w = 0.f;
        for (int s = 0; s < NS; ++s) w += S_img[(nn*NS+s)*CD + c];
        S_way[nn*CD + c] = w; tot += w;
    }
    S_tot[c] = tot;
}

// cds = sigmoid(d_intra/d_inter). grid (9,25), block 256 (64p x 4 c-chunks)
__global__ __launch_bounds__(256) void cds_v2(const float* __restrict__ lf, const float* __restrict__ invn,
                           const float* __restrict__ S_way, const float* __restrict__ S_img,
                           const float* __restrict__ S_tot, float* __restrict__ cds)
{
    const int b = blockIdx.y, t = threadIdx.x;
    const int p = blockIdx.x*64 + (t >> 2);
    const int cb = (t & 3) * 160;
    const int n = b / NS;
    const float* xp = lf + (size_t)b*CD*HWD + p + (size_t)cb*HWD;
    const float* wv = S_way + n*CD + cb;
    const float* iv = S_img + b*CD + cb;
    const float* tv = S_tot + cb;
    float dw = 0.f, di = 0.f, dt = 0.f, sq = 0.f;
    for (int c = 0; c < 160; ++c) {
        float v = xp[(size_t)c*HWD];
        dw = fmaf(v, wv[c], dw);
        di = fmaf(v, iv[c], di);
        dt = fmaf(v, tv[c], dt);
        sq = fmaf(v, v, sq);
    }
    dw += __shfl_xor(dw,1,64); dw += __shfl_xor(dw,2,64);
    di += __shfl_xor(di,1,64); di += __shfl_xor(di,2,64);
    dt += __shfl_xor(dt,1,64); dt += __shfl_xor(dt,2,64);
    sq += __shfl_xor(sq,1,64); sq += __shfl_xor(sq,2,64);
    if ((t & 3) == 0) {
        float in1 = invn[b*HWD + p];
        float d_intra = (in1 * dw - in1 * in1 * sq) * (1.f / 2880.f);
        float d_inter = (in1 * dt - in1 * di) * (1.f / 14400.f);
        float r = d_intra / d_inter;
        cds[n * NP + (b % NS) * HWD + p] = 1.f / (1.f + expf(-r));
    }
}

// exact top-2304-of-2880 per way, jax tie-break. grid 5, block 576
__global__ void topk_kernel(const float* __restrict__ cds, float* __restrict__ sel)
{
    __shared__ unsigned int u[NP];
    __shared__ int red[16];
    __shared__ int bcast;
    __shared__ int scanbuf[576];
    const int n = blockIdx.x, t = threadIdx.x;
    for (int j = t; j < NP; j += 576) {
        unsigned int x = __float_as_uint(cds[n * NP + j]);
        u[j] = (x & 0x80000000u) ? ~x : (x | 0x80000000u);
    }
    __syncthreads();
    const int j0 = t * 5;
    const int lane = t & 63, w = t >> 6;
    int kk = KTOP;
    unsigned int prefix = 0;
    for (int bit = 31; bit >= 0; --bit) {
        unsigned int want = (prefix >> bit) | 1u;
        int cnt = 0;
#pragma unroll
        for (int e = 0; e < 5; ++e) if ((u[j0+e] >> bit) == want) cnt++;
        for (int off = 32; off; off >>= 1) cnt += __shfl_down(cnt, off, 64);
        if (lane == 0) red[w] = cnt;
        __syncthreads();
        if (t == 0) { int s2 = 0; for (int q = 0; q < 9; ++q) s2 += red[q]; bcast = s2; }
        __syncthreads();
        int c1 = bcast;
        if (c1 >= kk) prefix |= (1u << bit);
        else kk -= c1;
        __syncthreads();
    }
    const unsigned int T = prefix;
    int cg = 0, ce = 0;
#pragma unroll
    for (int e = 0; e < 5; ++e) {
        unsigned v = u[j0+e];
        if (v > T) cg++; else if (v == T) ce++;
    }
    int r1 = cg;
    for (int off = 32; off; off >>= 1) r1 += __shfl_down(r1, off, 64);
    if (lane == 0) red[w] = r1;
    __syncthreads();
    if (t == 0) { int s2 = 0; for (int q = 0; q < 9; ++q) s2 += red[q]; bcast = s2; }
    __syncthreads();
    const int need = KTOP - bcast;
    scanbuf[t] = ce;
    __syncthreads();
    for (int off = 1; off < 576; off <<= 1) {
        int v2 = (t >= off) ? scanbuf[t - off] : 0;
        __syncthreads();
        scanbuf[t] += v2;
        __syncthreads();
    }
    int excl = scanbuf[t] - ce;
    int eidx = 0;
#pragma unroll
    for (int e = 0; e < 5; ++e) {
        int j = j0 + e;
        unsigned v = u[j];
        float s = 0.f;
        if (v > T) s = 1.f;
        else if (v == T) { if (excl + eidx < need) s = 1.f; eidx++; }
        int sh = j / HWD;
        sel[(n*NS + sh) * HWD + (j - sh*HWD)] = s;
    }
}

__global__ void closs_kernel(const float* __restrict__ Sm, float* __restrict__ out)
{
    int c = threadIdx.x;
    double A = 0.0, Bv = 0.0, Cv = 0.0;
    float tot = 0.f;
    for (int nn = 0; nn < NW; ++nn) {
        float ws = 0.f;
        for (int s = 0; s < NS; ++s) {
            float v = Sm[(nn*NS+s)*CD + c];
            ws += v; Cv += (double)v * v;
        }
        tot += ws; A += (double)ws * ws;
    }
    Bv = (double)tot * tot;
    int lane = c & 63, w = c >> 6;
    for (int off = 32; off; off >>= 1) {
        A  += __shfl_down(A,  off, 64);
        Bv += __shfl_down(Bv, off, 64);
        Cv += __shfl_down(Cv, off, 64);
    }
    __shared__ double sa[10], sb[10], sc[10];
    if (lane == 0) { sa[w] = A; sb[w] = Bv; sc[w] = Cv; }
    __syncthreads();
    if (c == 0) {
        double a = 0, b2 = 0, cc = 0;
        for (int q = 0; q < 10; ++q) { a += sa[q]; b2 += sb[q]; cc += sc[q]; }
        out[0] = (float)exp(5.0 * (a - cc) / (b2 - a));
    }
}

// per-pixel sum_c exp(X*gpa). grid (9,25), block 256 (64p x 4 c-chunks)
__global__ __launch_bounds__(256) void ctc_v2(const float* __restrict__ lf, const float* __restrict__ invn,
                           const float* __restrict__ proto1, const float* __restrict__ sel,
                           float* __restrict__ scal)
{
    const int b = blockIdx.y, t = threadIdx.x;
    const int p = blockIdx.x*64 + (t >> 2);
    const int cb = (t & 3) * 160;
    const int n = b / NS;
    const float* xp = lf + (size_t)b*CD*HWD + p + (size_t)cb*HWD;
    const float* pr = proto1 + n*CD + cb;
    float in1 = invn[b*HWD + p];
    float acc = 0.f;
    for (int c = 0; c < 160; ++c) acc += expf(xp[(size_t)c*HWD] * in1 * pr[c]);
    acc += __shfl_xor(acc, 1, 64); acc += __shfl_xor(acc, 2, 64);
    float pv = 0.f, nv = 0.f;
    if ((t & 3) == 0) {
        float s = sel[b*HWD + p];
        pv = (s > 0.5f) ? acc : 640.f;
        nv = (s > 0.5f) ? 640.f : acc;
    }
    for (int off = 32; off >= 4; off >>= 1) {
        pv += __shfl_down(pv, off, 64);
        nv += __shfl_down(nv, off, 64);
    }
    if ((t & 63) == 0) { atomicAdd(&scal[0], pv); atomicAdd(&scal[1], nv); }
}

__global__ void finalize_kernel(const float* __restrict__ scal, float* __restrict__ out)
{
    if (threadIdx.x == 0) out[1] = -(logf(scal[0]) - logf(scal[1]));
}

__global__ void posindex_kernel(const float* __restrict__ sel, float* __restrict__ out2)
{
    int idx = blockIdx.x * 256 + threadIdx.x;
    int row = idx / 144;
    int f4  = idx - row * 144;
    int b   = row / CD;
    const float* sp = sel + b * HWD + f4 * 4;
    float* op = out2 + (size_t)row * HWD + f4 * 4;
    float2 v0 = make_float2(sp[0], sp[1]);
    float2 v1 = make_float2(sp[2], sp[3]);
    *(float2*)op = v0; *(float2*)(op + 2) = v1;
}

__global__ void init_zero(float* __restrict__ cor, float* __restrict__ scal)
{
    int i = blockIdx.x * 256 + threadIdx.x;
    if (i < BB * HWD) cor[i] = 0.f;
    if (i < 2) scal[i] = 0.f;
}

extern "C" void kernel_launch(void* const* d_in, const int* in_sizes, int n_in,
                              void* d_out, int out_size, void* d_ws, size_t ws_size,
                              hipStream_t stream) {
    const float* lf = (const float*)d_in[0];
    const float* Wc = (const float*)d_in[1];
    const float* bc = (const float*)d_in[2];
    const float* Wq = (const float*)d_in[3];
    const float* bq = (const float*)d_in[4];
    const float* Wk = (const float*)d_in[5];
    const float* bk = (const float*)d_in[6];
    float* out = (float*)d_out;
    float* ws = (float*)d_ws;

    const size_t FEAT = 9216000;
    size_t off = 0;
    auto alloc = [&](size_t nf) { float* p = ws + off; off += (nf + 3) & ~(size_t)3; return p; };
    float* buf0   = alloc(FEAT);      // x5a -> w (fp32) -> Qh/Ql (bf16)
    float* buf1   = alloc(FEAT);      // x5 (fp32, stays live)
    float* xwp    = alloc(216000);    // 25 z x 3 jt x 2880
    int*   seedpx = (int*)alloc(32);
    float* seeds  = alloc(16000);
    float* invn5  = alloc(14400);
    float* invnl  = alloc(14400);
    float* cor    = alloc(14400);
    float* proto1 = alloc(3200);
    float* S_img  = alloc(16000);
    float* S_way  = alloc(3200);
    float* S_tot  = alloc(640);
    float* cds    = alloc(14400);
    float* sel    = alloc(14400);
    float* Sm     = alloc(16000);
    float* scal   = alloc(8);
    float* M2     = alloc(409600);
    float* wqtbk  = alloc(640);
    float* bqwk   = alloc(640);
    float* sbb    = alloc(4);
    float* rvec   = alloc(14400);

    // bf16 hi/lo buffers: K-side in the pos_index output region (overwritten last
    // by posindex_kernel), Q-side in buf0 (dead after w has been converted).
    unsigned short* Kh = (unsigned short*)(out + 2);
    unsigned short* Kl = Kh + FEAT;                 // 2*FEAT ushort = FEAT floats exactly
    unsigned short* Qh = (unsigned short*)buf0;
    unsigned short* Ql = Qh + FEAT;

    init_zero<<<57, 256, 0, stream>>>(cor, scal);

    // precompute M2 = Wq^T Wk and bias vectors
    mtm_kernel<<<dim3(10,10), 256, 0, stream>>>(Wq, Wk, M2);
    biasvec_kernel<<<1, 640, 0, stream>>>(Wq, Wk, bq, bk, wqtbk, bqwk, sbb);

    // conv chain (3 GEMMs; xq/xk folded into M2)
    conv_gemm<<<dim3(5,5,25), 256, 0, stream>>>(lf,   Wc, bc, lf,      buf0); // x5a
    conv_gemm<<<dim3(5,5,25), 256, 0, stream>>>(buf0, Wq, bq, nullptr, buf1); // x5
    conv_gemm<<<dim3(5,5,25), 256, 0, stream>>>(buf1, M2, wqtbk, nullptr, buf0); // w = (Wq^T Wk) x5 + Wq^T bk

    // convert to bf16 hi/lo (transposed rows): w -> K-side, then x5 -> Q-side
    convert_t<<<dim3(90,25), 256, 0, stream>>>(buf0, Kh, Kl);
    convert_t<<<dim3(90,25), 256, 0, stream>>>(buf1, Qh, Ql);
    rvec_kernel<<<dim3(9,25), 256, 0, stream>>>(buf1, bqwk, sbb, rvec);

    // QK^T (split-bf16 MFMA) with fused per-shot max
    qk_mfma<<<dim3(15,30,5), 256, 0, stream>>>(Qh, Ql, Kh, Kl, rvec, xwp);

    pixel_norms<<<dim3(9,25), 256, 0, stream>>>(buf1, invn5);
    pixel_norms<<<dim3(9,25), 256, 0, stream>>>(lf, invnl);
    xw_argmax<<<25, 576, 0, stream>>>(xwp, seedpx);
    seeds_gather<<<25, 640, 0, stream>>>(buf1, invn5, seedpx, seeds);
    cor_v2<<<dim3(9,25), 256, 0, stream>>>(buf1, invn5, seeds, cor);
    cor_minmax<<<25, 576, 0, stream>>>(cor);
    proto1_kernel<<<dim3(160,5), 256, 0, stream>>>(buf1, cor, proto1);

    // cdsnet
    masked_sum<<<dim3(160,25), 256, 0, stream>>>(lf, invnl, nullptr, S_img);
    sway_stot<<<1, 640, 0, stream>>>(S_img, S_way, S_tot);
    cds_v2<<<dim3(9,25), 256, 0, stream>>>(lf, invnl, S_way, S_img, S_tot, cds);
    topk_kernel<<<5, 576, 0, stream>>>(cds, sel);
    masked_sum<<<dim3(160,25), 256, 0, stream>>>(lf, invnl, sel, Sm);
    closs_kernel<<<1, 640, 0, stream>>>(Sm, out);            // out[0]

    // ctc
    ctc_v2<<<dim3(9,25), 256, 0, stream>>>(lf, invnl, proto1, sel, scal);
    finalize_kernel<<<1, 64, 0, stream>>>(scal, out);        // out[1]

    // pos_index (overwrites Kh/Kl scratch region)
    posindex_kernel<<<9000, 256, 0, stream>>>(sel, out + 2);
}

// Round 4
// 1181.406 us; speedup vs baseline: 1.4833x; 1.4487x over previous
//
#include <hip/hip_runtime.h>
#include <math.h>

#define NW 5
#define NS 5
#define BB 25            // NW*NS
#define CD 640
#define HWD 576
#define NP 2880          // NS*HWD
#define KTOP 2304        // int(2880*0.8)
#define EPSF 1e-12f

typedef __attribute__((ext_vector_type(8))) short short8;   // 8 bf16 (4 VGPRs)
typedef __attribute__((ext_vector_type(4))) float f32x4;

__device__ inline unsigned short f2bf(float x) {            // RNE float->bf16
    unsigned u = __float_as_uint(x);
    return (unsigned short)((u + 0x7fffu + ((u >> 16) & 1u)) >> 16);
}
__device__ inline float bf2f(unsigned short h) { return __uint_as_float(((unsigned)h) << 16); }

// async global->LDS, 16B per lane; LDS dest = wave-uniform base + lane*16
__device__ inline void gload_lds16(const void* g, void* l) {
    __builtin_amdgcn_global_load_lds(
        (const __attribute__((address_space(1))) unsigned int*)g,
        (__attribute__((address_space(3))) unsigned int*)l, 16, 0, 0);
}

// ---------------------------------------------------------------------------
// Tiled fp32 GEMM for conv1x1: out[b,o,p] = sum_c W[o,c]*in[b,c,p] + bias[o] (+res)
// tile 128(o) x 128(p), micro 8x8, K-chunk 16. grid (5 ptiles, 5 otiles, 25 b)
// ---------------------------------------------------------------------------
__global__ __launch_bounds__(256) void conv_gemm(
    const float* __restrict__ in, const float* __restrict__ W,
    const float* __restrict__ bias, const float* __restrict__ res,
    float* __restrict__ out)
{
    __shared__ __align__(16) float At[16][128];   // [kk][o]
    __shared__ __align__(16) float Bt[16][128];   // [kk][p]
    const int b  = blockIdx.z;
    const int o0 = blockIdx.y * 128;
    const int p0 = blockIdx.x * 128;
    const int t  = threadIdx.x;
    const int tx = t & 15, ty = t >> 4;

    float acc[8][8];
#pragma unroll
    for (int i = 0; i < 8; ++i)
#pragma unroll
        for (int j = 0; j < 8; ++j) acc[i][j] = 0.f;

    const int arow = t >> 1;
    const int ac   = (t & 1) * 8;
    const int brow = t >> 4;
    const int bp   = (t & 15) * 8;
    const bool bvalid = (p0 + bp) < HWD;
    const float* inb = in + (size_t)b * CD * HWD;

    for (int c0 = 0; c0 < CD; c0 += 16) {
        const float* wp = W + (size_t)(o0 + arow) * CD + c0 + ac;
        float4 wa = *(const float4*)wp;
        float4 wb = *(const float4*)(wp + 4);
        float4 ba, bb;
        if (bvalid) {
            const float* ip = inb + (size_t)(c0 + brow) * HWD + p0 + bp;
            ba = *(const float4*)ip; bb = *(const float4*)(ip + 4);
        } else { ba = make_float4(0.f,0.f,0.f,0.f); bb = ba; }
        __syncthreads();
        At[ac+0][arow]=wa.x; At[ac+1][arow]=wa.y; At[ac+2][arow]=wa.z; At[ac+3][arow]=wa.w;
        At[ac+4][arow]=wb.x; At[ac+5][arow]=wb.y; At[ac+6][arow]=wb.z; At[ac+7][arow]=wb.w;
        *(float4*)&Bt[brow][bp]   = ba;
        *(float4*)&Bt[brow][bp+4] = bb;
        __syncthreads();
#pragma unroll
        for (int kk = 0; kk < 16; ++kk) {
            float4 a0 = *(const float4*)&At[kk][ty*8];
            float4 a1 = *(const float4*)&At[kk][ty*8+4];
            float4 b0 = *(const float4*)&Bt[kk][tx*8];
            float4 b1 = *(const float4*)&Bt[kk][tx*8+4];
            float av[8] = {a0.x,a0.y,a0.z,a0.w,a1.x,a1.y,a1.z,a1.w};
            float bv[8] = {b0.x,b0.y,b0.z,b0.w,b1.x,b1.y,b1.z,b1.w};
#pragma unroll
            for (int i = 0; i < 8; ++i)
#pragma unroll
                for (int j = 0; j < 8; ++j)
                    acc[i][j] = fmaf(av[i], bv[j], acc[i][j]);
        }
    }

    if ((p0 + tx*8) < HWD) {
#pragma unroll
        for (int r = 0; r < 8; ++r) {
            int o = o0 + ty*8 + r;
            float bs = bias[o];
            float* op = out + ((size_t)b*CD + o)*HWD + p0 + tx*8;
            float4 v0, v1;
            v0.x=acc[r][0]+bs; v0.y=acc[r][1]+bs; v0.z=acc[r][2]+bs; v0.w=acc[r][3]+bs;
            v1.x=acc[r][4]+bs; v1.y=acc[r][5]+bs; v1.z=acc[r][6]+bs; v1.w=acc[r][7]+bs;
            if (res != nullptr) {
                const float* rp = res + ((size_t)b*CD + o)*HWD + p0 + tx*8;
                float4 r0 = *(const float4*)rp; float4 r1 = *(const float4*)(rp+4);
                v0.x+=r0.x; v0.y+=r0.y; v0.z+=r0.z; v0.w+=r0.w;
                v1.x+=r1.x; v1.y+=r1.y; v1.z+=r1.z; v1.w+=r1.w;
            }
            *(float4*)op = v0; *(float4*)(op+4) = v1;
        }
    }
}

// M2[o][c] = sum_m Wq[m][o]*Wk[m][c]   (Wq^T Wk). grid (10,10), block 256, 4x4/thread
__global__ __launch_bounds__(256) void mtm_kernel(
    const float* __restrict__ Wq, const float* __restrict__ Wk, float* __restrict__ M2)
{
    const int o0 = blockIdx.y*64 + (threadIdx.x >> 4)*4;
    const int j0 = blockIdx.x*64 + (threadIdx.x & 15)*4;
    float acc[4][4];
#pragma unroll
    for (int r = 0; r < 4; ++r)
#pragma unroll
        for (int s = 0; s < 4; ++s) acc[r][s] = 0.f;
    for (int c = 0; c < CD; ++c) {
        float4 a = *(const float4*)&Wq[(size_t)c*CD + o0];
        float4 b2 = *(const float4*)&Wk[(size_t)c*CD + j0];
        float av[4] = {a.x,a.y,a.z,a.w}, bv[4] = {b2.x,b2.y,b2.z,b2.w};
#pragma unroll
        for (int r = 0; r < 4; ++r)
#pragma unroll
            for (int s = 0; s < 4; ++s) acc[r][s] = fmaf(av[r], bv[s], acc[r][s]);
    }
#pragma unroll
    for (int r = 0; r < 4; ++r)
#pragma unroll
        for (int s = 0; s < 4; ++s) M2[(size_t)(o0+r)*CD + j0 + s] = acc[r][s];
}

// wqtbk[o] = sum_m Wq[m][o]*bk[m];  bqwk[j] = sum_m bq[m]*Wk[m][j];  sbb = bq.bk
__global__ void biasvec_kernel(const float* __restrict__ Wq, const float* __restrict__ Wk,
                               const float* __restrict__ bq, const float* __restrict__ bk,
                               float* __restrict__ wqtbk, float* __restrict__ bqwk,
                               float* __restrict__ sbb)
{
    int c = threadIdx.x;
    float s1 = 0.f, s2 = 0.f;
    for (int m = 0; m < CD; ++m) {
        s1 = fmaf(Wq[(size_t)m*CD + c], bk[m], s1);
        s2 = fmaf(bq[m], Wk[(size_t)m*CD + c], s2);
    }
    wqtbk[c] = s1; bqwk[c] = s2;
    if (c == 0) { float s3 = 0.f; for (int m = 0; m < CD; ++m) s3 = fmaf(bq[m], bk[m], s3); sbb[0] = s3; }
}

// rvec[b*576+p] = sum_c x5[b][c][p]*bqwk[c] + sbb. grid (9,25), block 256
__global__ __launch_bounds__(256) void rvec_kernel(const float* __restrict__ x5,
                                                   const float* __restrict__ bqwk,
                                                   const float* __restrict__ sbb,
                                                   float* __restrict__ rvec)
{
    const int b = blockIdx.y, t = threadIdx.x;
    const int p = blockIdx.x*64 + (t >> 2);
    const int cb = (t & 3) * 160;
    const float* xp = x5 + (size_t)b*CD*HWD + p + (size_t)cb*HWD;
    const float* wv = bqwk + cb;
    float a = 0.f;
    for (int c = 0; c < 160; ++c) a = fmaf(xp[(size_t)c*HWD], wv[c], a);
    a += __shfl_xor(a, 1, 64); a += __shfl_xor(a, 2, 64);
    if ((t & 3) == 0) rvec[b*HWD + p] = a + sbb[0];
}

// ---------------------------------------------------------------------------
// Transpose + bf16 hi/lo split: in [b][c][p] fp32 -> Oh/Ol rows [b*576+p][c].
// grid (90 = 10 ctiles x 9 ptiles, 25 b), block 256, 64x64 tiles.
// ---------------------------------------------------------------------------
__global__ __launch_bounds__(256) void convert_t(const float* __restrict__ in,
        unsigned short* __restrict__ Oh, unsigned short* __restrict__ Ol)
{
    __shared__ float tile[64][65];
    const int b  = blockIdx.y;
    const int c0 = (blockIdx.x / 9) * 64;
    const int p0 = (blockIdx.x % 9) * 64;
    const int t  = threadIdx.x;
    const float* src = in + (size_t)b * CD * HWD;
#pragma unroll
    for (int it = 0; it < 4; ++it) {
        int cl = (t >> 4) + 16*it, pl = (t & 15) * 4;
        float4 v = *(const float4*)&src[(size_t)(c0+cl)*HWD + p0 + pl];
        tile[cl][pl] = v.x; tile[cl][pl+1] = v.y; tile[cl][pl+2] = v.z; tile[cl][pl+3] = v.w;
    }
    __syncthreads();
#pragma unroll
    for (int it = 0; it < 4; ++it) {
        int pl = (t >> 4) + 16*it, clb = (t & 15) * 4;
        ushort4 hv, lv;
        float x0 = tile[clb+0][pl], x1 = tile[clb+1][pl], x2 = tile[clb+2][pl], x3 = tile[clb+3][pl];
        hv.x = f2bf(x0); hv.y = f2bf(x1); hv.z = f2bf(x2); hv.w = f2bf(x3);
        lv.x = f2bf(x0 - bf2f(hv.x)); lv.y = f2bf(x1 - bf2f(hv.y));
        lv.z = f2bf(x2 - bf2f(hv.z)); lv.w = f2bf(x3 - bf2f(hv.w));
        size_t o = (size_t)(b*HWD + p0 + pl) * CD + c0 + clb;
        *(ushort4*)&Oh[o] = hv;
        *(ushort4*)&Ol[o] = lv;
    }
}

// ---------------------------------------------------------------------------
// S = Q . K^T via split-bf16 MFMA (3-term: hh + hl + lh), fused per-key-shot max.
// Staging via global_load_lds (no VGPR round-trip, no scratch spill).
// grid (30 itiles [x, fastest: 30 consecutive blocks share one K-tile via L2],
//       15 = shot*3+jt [y], 5 n [z]), block 256.
// LDS rows (64B each): Ah rows 0..95 | Al 96..191 | Bh 192..383 | Bl 384..575.
// Region boundaries are multiples of 16 -> each 16-row segment is uniform.
// ---------------------------------------------------------------------------
__global__ __launch_bounds__(256) void qk_mfma(
    const unsigned short* __restrict__ Qh, const unsigned short* __restrict__ Ql,
    const unsigned short* __restrict__ Kh, const unsigned short* __restrict__ Kl,
    const float* __restrict__ rvec, float* __restrict__ xwp)
{
    __shared__ __align__(16) unsigned short lds[18432];     // 36 KB
    const int n    = blockIdx.z;
    const int i0   = blockIdx.x * 96;
    const int shot = blockIdx.y / 3;
    const int jt   = blockIdx.y % 3;
    const int t    = threadIdx.x;
    const int w    = t >> 6, lane = t & 63;
    const int ihalf = (w & 1) * 48;
    const int jhalf = (w >> 1) * 96;

    const size_t qbase = (size_t)(n*NP + i0) * CD;
    const size_t kbase = (size_t)(n*NP + shot*HWD + jt*192) * CD;

    f32x4 acc[3][6];
#pragma unroll
    for (int f = 0; f < 3; ++f)
#pragma unroll
        for (int g = 0; g < 6; ++g) acc[f][g] = (f32x4){0.f,0.f,0.f,0.f};

    const int rl = lane >> 2;         // row within 16-row segment
    const int cl = (lane & 3) * 8;    // bf16 col offset within 32-wide chunk

    for (int c0 = 0; c0 < CD; c0 += 32) {
        // stage 36 KB: 36 segments of 16 rows x 64B; wave w issues segs w*9..w*9+8
#pragma unroll
        for (int e = 0; e < 9; ++e) {
            const int s = w*9 + e;
            const int r = s*16 + rl;          // row in 576-row layout
            const unsigned short* src;
            if (s < 6)        src = Qh + qbase + (size_t)r*CD        + c0 + cl;
            else if (s < 12)  src = Ql + qbase + (size_t)(r-96)*CD   + c0 + cl;
            else if (s < 24)  src = Kh + kbase + (size_t)(r-192)*CD  + c0 + cl;
            else              src = Kl + kbase + (size_t)(r-384)*CD  + c0 + cl;
            gload_lds16(src, &lds[s*512]);    // dest uniform per (w,e)
        }
        __syncthreads();                       // vmcnt(0) drain + barrier

        const int chunk = (lane >> 4) * 8;
        short8 afh[3], afl[3];
#pragma unroll
        for (int f = 0; f < 3; ++f) {
            int row = ihalf + f*16 + (lane & 15);
            afh[f] = *(const short8*)&lds[row*32 + chunk];
            afl[f] = *(const short8*)&lds[3072 + row*32 + chunk];
        }
#pragma unroll
        for (int g = 0; g < 6; ++g) {
            int row = jhalf + g*16 + (lane & 15);
            short8 bfh = *(const short8*)&lds[6144  + row*32 + chunk];
            short8 bfl = *(const short8*)&lds[12288 + row*32 + chunk];
#pragma unroll
            for (int f = 0; f < 3; ++f) {
                acc[f][g] = __builtin_amdgcn_mfma_f32_16x16x32_bf16(afh[f], bfh, acc[f][g], 0, 0, 0);
                acc[f][g] = __builtin_amdgcn_mfma_f32_16x16x32_bf16(afh[f], bfl, acc[f][g], 0, 0, 0);
                acc[f][g] = __builtin_amdgcn_mfma_f32_16x16x32_bf16(afl[f], bfh, acc[f][g], 0, 0, 0);
            }
        }
        __syncthreads();                       // protect LDS before next overwrite
    }

    // epilogue: add rvec[j], max over this block's 192 keys, per query row
    float rv[6];
    {
        int jg0 = n*NP + shot*HWD + jt*192 + jhalf + (lane & 15);
#pragma unroll
        for (int g = 0; g < 6; ++g) rv[g] = rvec[jg0 + g*16];
    }
    float* smax = (float*)lds;      // [96][2]
#pragma unroll
    for (int f = 0; f < 3; ++f) {
#pragma unroll
        for (int r = 0; r < 4; ++r) {
            float m = -INFINITY;
#pragma unroll
            for (int g = 0; g < 6; ++g) m = fmaxf(m, acc[f][g][r] + rv[g]);
#pragma unroll
            for (int off = 1; off < 16; off <<= 1) m = fmaxf(m, __shfl_xor(m, off, 64));
            if ((lane & 15) == 0) smax[(ihalf + f*16 + (lane >> 4)*4 + r)*2 + (w >> 1)] = m;
        }
    }
    __syncthreads();
    if (t < 96) {
        float m = fmaxf(smax[t*2], smax[t*2 + 1]);
        xwp[(((size_t)n*5 + shot)*3 + jt)*NP + i0 + t] = m;
    }
}

// x_w[n,i] ~ sum_s max_jt xwp  (scale/softmax dropped: argmax-invariant)
__global__ void xw_argmax(const float* __restrict__ xwp, int* __restrict__ seed_pix)
{
    const int b = blockIdx.x;
    const int n = b / NS, sq = b % NS;
    const int p = threadIdx.x;
    const int i = sq * HWD + p;
    float v = 0.f;
#pragma unroll
    for (int s = 0; s < NS; ++s) {
        float m = -INFINITY;
#pragma unroll
        for (int tt = 0; tt < 3; ++tt)
            m = fmaxf(m, xwp[(((size_t)(n*NS+s))*3 + tt)*NP + i]);
        v += m;
    }
    int lane = p & 63, w = p >> 6;
    float bv = v; int bi = p;
    for (int off = 32; off; off >>= 1) {
        float ov = __shfl_down(bv, off, 64);
        int   oi = __shfl_down(bi, off, 64);
        if (ov > bv || (ov == bv && oi < bi)) { bv = ov; bi = oi; }
    }
    __shared__ float wv[9]; __shared__ int wi[9];
    if (lane == 0) { wv[w] = bv; wi[w] = bi; }
    __syncthreads();
    if (p == 0) {
        float best = wv[0]; int bidx = wi[0];
        for (int k = 1; k < 9; ++k)
            if (wv[k] > best || (wv[k] == best && wi[k] < bidx)) { best = wv[k]; bidx = wi[k]; }
        seed_pix[b] = bidx;
    }
}

// per-pixel inverse L2 norm. grid (9,25), block 256 (64 pixels x 4 c-chunks)
__global__ __launch_bounds__(256) void pixel_norms(const float* __restrict__ src, float* __restrict__ invn)
{
    const int b = blockIdx.y, t = threadIdx.x;
    const int p = blockIdx.x*64 + (t >> 2);
    const int cb = (t & 3) * 160;
    const float* sp = src + (size_t)b*CD*HWD + p + (size_t)cb*HWD;
    float a = 0.f;
    for (int c = 0; c < 160; ++c) { float v = sp[(size_t)c*HWD]; a = fmaf(v, v, a); }
    a += __shfl_xor(a, 1, 64); a += __shfl_xor(a, 2, 64);
    if ((t & 3) == 0) invn[b*HWD + p] = 1.f / fmaxf(sqrtf(a), EPSF);
}

__global__ void seeds_gather(const float* __restrict__ x5, const float* __restrict__ invn5,
                             const int* __restrict__ seed_pix, float* __restrict__ seeds)
{
    int b = blockIdx.x, c = threadIdx.x;
    int pix = seed_pix[b];
    seeds[b * CD + c] = x5[((size_t)b * CD + c) * HWD + pix] * invn5[b * HWD + pix];
}

// cor[n,o,p] += invn5 * sum_c x5*seeds, x5 read once for all 5 o. grid (9, 25 b=(n,k))
__global__ __launch_bounds__(256) void cor_v2(const float* __restrict__ x5, const float* __restrict__ invn5,
                           const float* __restrict__ seeds, float* __restrict__ cor)
{
    const int b = blockIdx.y;
    const int n = b / NS, k = b % NS;
    const int t = threadIdx.x;
    const int p = blockIdx.x*64 + (t >> 2);
    const int cb = (t & 3) * 160;
    const float* xp = x5 + (size_t)b*CD*HWD + p;
    float a[5] = {0.f,0.f,0.f,0.f,0.f};
    for (int c = 0; c < 160; ++c) {
        float v = xp[(size_t)(cb + c)*HWD];
#pragma unroll
        for (int o = 0; o < 5; ++o)
            a[o] = fmaf(v, seeds[(o*NS + k)*CD + cb + c], a[o]);
    }
    float in1 = invn5[b*HWD + p];
#pragma unroll
    for (int o = 0; o < 5; ++o) {
        float s = a[o];
        s += __shfl_xor(s, 1, 64); s += __shfl_xor(s, 2, 64);
        if ((t & 3) == 0) atomicAdd(&cor[(n*5 + o)*HWD + p], in1 * s);
    }
}

__global__ void cor_minmax(float* __restrict__ cor)
{
    int z = blockIdx.x; int p = threadIdx.x;
    float v = cor[z * HWD + p];
    float mn = v, mx = v;
    for (int off = 32; off; off >>= 1) {
        mn = fminf(mn, __shfl_xor(mn, off, 64));
        mx = fmaxf(mx, __shfl_xor(mx, off, 64));
    }
    __shared__ float smn[9], smx[9];
    int lane = p & 63, w = p >> 6;
    if (lane == 0) { smn[w] = mn; smx[w] = mx; }
    __syncthreads();
    __shared__ float fmn, fmx;
    if (p == 0) {
        float a = smn[0], b = smx[0];
        for (int k = 1; k < 9; ++k) { a = fminf(a, smn[k]); b = fmaxf(b, smx[k]); }
        fmn = a; fmx = b;
    }
    __syncthreads();
    cor[z * HWD + p] = (v - fmn) / (fmx - fmn + EPSF);
}

__global__ void proto1_kernel(const float* __restrict__ x5, const float* __restrict__ cor,
                              float* __restrict__ proto1)
{
    int n = blockIdx.y; int ct = blockIdx.x;
    int t = threadIdx.x; int pi = t & 63, cj = t >> 6;
    int c = ct * 4 + cj;
    float acc = 0.f;
    for (int s = 0; s < NS; ++s) {
        const float* xp = x5 + ((size_t)(n*NS+s) * CD + c) * HWD;
        const float* wp = cor + (size_t)(n*NS+s) * HWD;
        for (int p = pi; p < HWD; p += 64) acc = fmaf(xp[p], wp[p], acc);
    }
    for (int off = 32; off; off >>= 1) acc += __shfl_down(acc, off, 64);
    if (pi == 0) proto1[n * CD + c] = acc * (1.f / 2880.f);
}

__global__ void masked_sum(const float* __restrict__ lf, const float* __restrict__ invn,
                           const float* __restrict__ mask, float* __restrict__ out)
{
    int b = blockIdx.y; int ct = blockIdx.x;
    int t = threadIdx.x; int pi = t & 63, cj = t >> 6;
    int c = ct * 4 + cj;
    const float* xp = lf + ((size_t)b * CD + c) * HWD;
    const float* ip = invn + b * HWD;
    float acc = 0.f;
    if (mask != nullptr) {
        const float* mp = mask + b * HWD;
        for (int p = pi; p < HWD; p += 64) acc = fmaf(xp[p], ip[p] * mp[p], acc);
    } else {
        for (int p = pi; p < HWD; p += 64) acc = fmaf(xp[p], ip[p], acc);
    }
    for (int off = 32; off; off >>= 1) acc += __shfl_down(acc, off, 64);
    if (pi == 0) out[b * CD + c] = acc;
}

__global__ void sway_stot(const float* __restrict__ S_img, float* __restrict__ S_way,
                          float* __restrict__ S_tot)
{
    int c = threadIdx.x;
    float tot = 0.f;
    for (int nn = 0; nn < NW; ++nn) {
        float w = 0.f;
        for (int s = 0; s < NS; ++s) w += S_img[(nn*NS+s)*CD + c];
        S_way[nn*CD + c] = w; tot += w;
    }
    S_tot[c] = tot;
}

// cds = sigmoid(d_intra/d_inter). grid (9,25), block 256 (64p x 4 c-chunks)
__global__ __launch_bounds__(256) void cds_v2(const float* __restrict__ lf, const float* __restrict__ invn,
                           const float* __restrict__ S_way, const float* __restrict__ S_img,
                           const float* __restrict__ S_tot, float* __restrict__ cds)
{
    const int b = blockIdx.y, t = threadIdx.x;
    const int p = blockIdx.x*64 + (t >> 2);
    const int cb = (t & 3) * 160;
    const int n = b / NS;
    const float* xp = lf + (size_t)b*CD*HWD + p + (size_t)cb*HWD;
    const float* wv = S_way + n*CD + cb;
    const float* iv = S_img + b*CD + cb;
    const float* tv = S_tot + cb;
    float dw = 0.f, di = 0.f, dt = 0.f, sq = 0.f;
    for (int c = 0; c < 160; ++c) {
        float v = xp[(size_t)c*HWD];
        dw = fmaf(v, wv[c], dw);
        di = fmaf(v, iv[c], di);
        dt = fmaf(v, tv[c], dt);
        sq = fmaf(v, v, sq);
    }
    dw += __shfl_xor(dw,1,64); dw += __shfl_xor(dw,2,64);
    di += __shfl_xor(di,1,64); di += __shfl_xor(di,2,64);
    dt += __shfl_xor(dt,1,64); dt += __shfl_xor(dt,2,64);
    sq += __shfl_xor(sq,1,64); sq += __shfl_xor(sq,2,64);
    if ((t & 3) == 0) {
        float in1 = invn[b*HWD + p];
        float d_intra = (in1 * dw - in1 * in1 * sq) * (1.f / 2880.f);
        float d_inter = (in1 * dt - in1 * di) * (1.f / 14400.f);
        float r = d_intra / d_inter;
        cds[n * NP + (b % NS) * HWD + p] = 1.f / (1.f + expf(-r));
    }
}

// exact top-2304-of-2880 per way, jax tie-break. grid 5, block 576
__global__ void topk_kernel(const float* __restrict__ cds, float* __restrict__ sel)
{
    __shared__ unsigned int u[NP];
    __shared__ int red[16];
    __shared__ int bcast;
    __shared__ int scanbuf[576];
    const int n = blockIdx.x, t = threadIdx.x;
    for (int j = t; j < NP; j += 576) {
        unsigned int x = __float_as_uint(cds[n * NP + j]);
        u[j] = (x & 0x80000000u) ? ~x : (x | 0x80000000u);
    }
    __syncthreads();
    const int j0 = t * 5;
    const int lane = t & 63, w = t >> 6;
    int kk = KTOP;
    unsigned int prefix = 0;
    for (int bit = 31; bit >= 0; --bit) {
        unsigned int want = (prefix >> bit) | 1u;
        int cnt = 0;
#pragma unroll
        for (int e = 0; e < 5; ++e) if ((u[j0+e] >> bit) == want) cnt++;
        for (int off = 32; off; off >>= 1) cnt += __shfl_down(cnt, off, 64);
        if (lane == 0) red[w] = cnt;
        __syncthreads();
        if (t == 0) { int s2 = 0; for (int q = 0; q < 9; ++q) s2 += red[q]; bcast = s2; }
        __syncthreads();
        int c1 = bcast;
        if (c1 >= kk) prefix |= (1u << bit);
        else kk -= c1;
        __syncthreads();
    }
    const unsigned int T = prefix;
    int cg = 0, ce = 0;
#pragma unroll
    for (int e = 0; e < 5; ++e) {
        unsigned v = u[j0+e];
        if (v > T) cg++; else if (v == T) ce++;
    }
    int r1 = cg;
    for (int off = 32; off; off >>= 1) r1 += __shfl_down(r1, off, 64);
    if (lane == 0) red[w] = r1;
    __syncthreads();
    if (t == 0) { int s2 = 0; for (int q = 0; q < 9; ++q) s2 += red[q]; bcast = s2; }
    __syncthreads();
    const int need = KTOP - bcast;
    scanbuf[t] = ce;
    __syncthreads();
    for (int off = 1; off < 576; off <<= 1) {
        int v2 = (t >= off) ? scanbuf[t - off] : 0;
        __syncthreads();
        scanbuf[t] += v2;
        __syncthreads();
    }
    int excl = scanbuf[t] - ce;
    int eidx = 0;
#pragma unroll
    for (int e = 0; e < 5; ++e) {
        int j = j0 + e;
        unsigned v = u[j];
        float s = 0.f;
        if (v > T) s = 1.f;
        else if (v == T) { if (excl + eidx < need) s = 1.f; eidx++; }
        int sh = j / HWD;
        sel[(n*NS + sh) * HWD + (j - sh*HWD)] = s;
    }
}

__global__ void closs_kernel(const float* __restrict__ Sm, float* __restrict__ out)
{
    int c = threadIdx.x;
    double A = 0.0, Bv = 0.0, Cv = 0.0;
    float tot = 0.f;
    for (int nn = 0; nn < NW; ++nn) {
        float ws = 0.f;
        for (int s = 0; s < NS; ++s) {
            float v = Sm[(nn*NS+s)*CD + c];
            ws += v; Cv += (double)v * v;
        }
        tot += ws; A += (double)ws * ws;
    }
    Bv = (double)tot * tot;
    int lane = c & 63, w = c >> 6;
    for (int off = 32; off; off >>= 1) {
        A  += __shfl_down(A,  off, 64);
        Bv += __shfl_down(Bv, off, 64);
        Cv += __shfl_down(Cv, off, 64);
    }
    __shared__ double sa[10], sb[10], sc[10];
    if (lane == 0) { sa[w] = A; sb[w] = Bv; sc[w] = Cv; }
    __syncthreads();
    if (c == 0) {
        double a = 0, b2 = 0, cc = 0;
        for (int q = 0; q < 10; ++q) { a += sa[q]; b2 += sb[q]; cc += sc[q]; }
        out[0] = (float)exp(5.0 * (a - cc) / (b2 - a));
    }
}

// per-pixel sum_c exp(X*gpa). grid (9,25), block 256 (64p x 4 c-chunks)
__global__ __launch_bounds__(256) void ctc_v2(const float* __restrict__ lf, const float* __restrict__ invn,
                           const float* __restrict__ proto1, const float* __restrict__ sel,
                           float* __restrict__ scal)
{
    const int b = blockIdx.y, t = threadIdx.x;
    const int p = blockIdx.x*64 + (t >> 2);
    const int cb = (t & 3) * 160;
    const int n = b / NS;
    const float* xp = lf + (size_t)b*CD*HWD + p + (size_t)cb*HWD;
    const float* pr = proto1 + n*CD + cb;
    float in1 = invn[b*HWD + p];
    float acc = 0.f;
    for (int c = 0; c < 160; ++c) acc += expf(xp[(size_t)c*HWD] * in1 * pr[c]);
    acc += __shfl_xor(acc, 1, 64); acc += __shfl_xor(acc, 2, 64);
    float pv = 0.f, nv = 0.f;
    if ((t & 3) == 0) {
        float s = sel[b*HWD + p];
        pv = (s > 0.5f) ? acc : 640.f;
        nv = (s > 0.5f) ? 640.f : acc;
    }
    for (int off = 32; off >= 4; off >>= 1) {
        pv += __shfl_down(pv, off, 64);
        nv += __shfl_down(nv, off, 64);
    }
    if ((t & 63) == 0) { atomicAdd(&scal[0], pv); atomicAdd(&scal[1], nv); }
}

__global__ void finalize_kernel(const float* __restrict__ scal, float* __restrict__ out)
{
    if (threadIdx.x == 0) out[1] = -(logf(scal[0]) - logf(scal[1]));
}

__global__ void posindex_kernel(const float* __restrict__ sel, float* __restrict__ out2)
{
    int idx = blockIdx.x * 256 + threadIdx.x;
    int row = idx / 144;
    int f4  = idx - row * 144;
    int b   = row / CD;
    const float* sp = sel + b * HWD + f4 * 4;
    float* op = out2 + (size_t)row * HWD + f4 * 4;
    float2 v0 = make_float2(sp[0], sp[1]);
    float2 v1 = make_float2(sp[2], sp[3]);
    *(float2*)op = v0; *(float2*)(op + 2) = v1;
}

__global__ void init_zero(float* __restrict__ cor, float* __restrict__ scal)
{
    int i = blockIdx.x * 256 + threadIdx.x;
    if (i < BB * HWD) cor[i] = 0.f;
    if (i < 2) scal[i] = 0.f;
}

extern "C" void kernel_launch(void* const* d_in, const int* in_sizes, int n_in,
                              void* d_out, int out_size, void* d_ws, size_t ws_size,
                              hipStream_t stream) {
    const float* lf = (const float*)d_in[0];
    const float* Wc = (const float*)d_in[1];
    const float* bc = (const float*)d_in[2];
    const float* Wq = (const float*)d_in[3];
    const float* bq = (const float*)d_in[4];
    const float* Wk = (const float*)d_in[5];
    const float* bk = (const float*)d_in[6];
    float* out = (float*)d_out;
    float* ws = (float*)d_ws;

    const size_t FEAT = 9216000;
    size_t off = 0;
    auto alloc = [&](size_t nf) { float* p = ws + off; off += (nf + 3) & ~(size_t)3; return p; };
    float* buf0   = alloc(FEAT);      // x5a -> w (fp32) -> Qh/Ql (bf16)
    float* buf1   = alloc(FEAT);      // x5 (fp32, stays live)
    float* xwp    = alloc(216000);    // 25 z x 3 jt x 2880
    int*   seedpx = (int*)alloc(32);
    float* seeds  = alloc(16000);
    float* invn5  = alloc(14400);
    float* invnl  = alloc(14400);
    float* cor    = alloc(14400);
    float* proto1 = alloc(3200);
    float* S_img  = alloc(16000);
    float* S_way  = alloc(3200);
    float* S_tot  = alloc(640);
    float* cds    = alloc(14400);
    float* sel    = alloc(14400);
    float* Sm     = alloc(16000);
    float* scal   = alloc(8);
    float* M2     = alloc(409600);
    float* wqtbk  = alloc(640);
    float* bqwk   = alloc(640);
    float* sbb    = alloc(4);
    float* rvec   = alloc(14400);

    // bf16 hi/lo buffers: K-side in the pos_index output region (overwritten last
    // by posindex_kernel), Q-side in buf0 (dead after w has been converted).
    unsigned short* Kh = (unsigned short*)(out + 2);
    unsigned short* Kl = Kh + FEAT;                 // 2*FEAT ushort = FEAT floats exactly
    unsigned short* Qh = (unsigned short*)buf0;
    unsigned short* Ql = Qh + FEAT;

    init_zero<<<57, 256, 0, stream>>>(cor, scal);

    // precompute M2 = Wq^T Wk and bias vectors
    mtm_kernel<<<dim3(10,10), 256, 0, stream>>>(Wq, Wk, M2);
    biasvec_kernel<<<1, 640, 0, stream>>>(Wq, Wk, bq, bk, wqtbk, bqwk, sbb);

    // conv chain (3 GEMMs; xq/xk folded into M2)
    conv_gemm<<<dim3(5,5,25), 256, 0, stream>>>(lf,   Wc, bc, lf,      buf0); // x5a
    conv_gemm<<<dim3(5,5,25), 256, 0, stream>>>(buf0, Wq, bq, nullptr, buf1); // x5
    conv_gemm<<<dim3(5,5,25), 256, 0, stream>>>(buf1, M2, wqtbk, nullptr, buf0); // w = (Wq^T Wk) x5 + Wq^T bk

    // convert to bf16 hi/lo (transposed rows): w -> K-side, then x5 -> Q-side
    convert_t<<<dim3(90,25), 256, 0, stream>>>(buf0, Kh, Kl);
    convert_t<<<dim3(90,25), 256, 0, stream>>>(buf1, Qh, Ql);
    rvec_kernel<<<dim3(9,25), 256, 0, stream>>>(buf1, bqwk, sbb, rvec);

    // QK^T (split-bf16 MFMA) with fused per-shot max
    qk_mfma<<<dim3(30,15,5), 256, 0, stream>>>(Qh, Ql, Kh, Kl, rvec, xwp);

    pixel_norms<<<dim3(9,25), 256, 0, stream>>>(buf1, invn5);
    pixel_norms<<<dim3(9,25), 256, 0, stream>>>(lf, invnl);
    xw_argmax<<<25, 576, 0, stream>>>(xwp, seedpx);
    seeds_gather<<<25, 640, 0, stream>>>(buf1, invn5, seedpx, seeds);
    cor_v2<<<dim3(9,25), 256, 0, stream>>>(buf1, invn5, seeds, cor);
    cor_minmax<<<25, 576, 0, stream>>>(cor);
    proto1_kernel<<<dim3(160,5), 256, 0, stream>>>(buf1, cor, proto1);

    // cdsnet
    masked_sum<<<dim3(160,25), 256, 0, stream>>>(lf, invnl, nullptr, S_img);
    sway_stot<<<1, 640, 0, stream>>>(S_img, S_way, S_tot);
    cds_v2<<<dim3(9,25), 256, 0, stream>>>(lf, invnl, S_way, S_img, S_tot, cds);
    topk_kernel<<<5, 576, 0, stream>>>(cds, sel);
    masked_sum<<<dim3(160,25), 256, 0, stream>>>(lf, invnl, sel, Sm);
    closs_kernel<<<1, 640, 0, stream>>>(Sm, out);            // out[0]

    // ctc
    ctc_v2<<<dim3(9,25), 256, 0, stream>>>(lf, invnl, proto1, sel, scal);
    finalize_kernel<<<1, 64, 0, stream>>>(scal, out);        // out[1]

    // pos_index (overwrites Kh/Kl scratch region)
    posindex_kernel<<<9000, 256, 0, stream>>>(sel, out + 2);
}

// Round 5
// 906.248 us; speedup vs baseline: 1.9337x; 1.3036x over previous
//
#include <hip/hip_runtime.h>
#include <math.h>

#define NW 5
#define NS 5
#define BB 25            // NW*NS
#define CD 640
#define HWD 576
#define NP 2880          // NS*HWD
#define KTOP 2304        // int(2880*0.8)
#define EPSF 1e-12f

typedef __attribute__((ext_vector_type(8))) short short8;   // 8 bf16 (4 VGPRs)
typedef __attribute__((ext_vector_type(4))) float f32x4;

__device__ inline unsigned short f2bf(float x) {            // RNE float->bf16
    unsigned u = __float_as_uint(x);
    return (unsigned short)((u + 0x7fffu + ((u >> 16) & 1u)) >> 16);
}
__device__ inline float bf2f(unsigned short h) { return __uint_as_float(((unsigned)h) << 16); }

// async global->LDS, 16B per lane; LDS dest = wave-uniform base + lane*16
__device__ inline void gload_lds16(const void* g, void* l) {
    __builtin_amdgcn_global_load_lds(
        (const __attribute__((address_space(1))) unsigned int*)g,
        (__attribute__((address_space(3))) unsigned int*)l, 16, 0, 0);
}

// M2[o][c] = sum_m Wq[m][o]*Wk[m][c]   (Wq^T Wk). grid (10,10), block 256, 4x4/thread
__global__ __launch_bounds__(256) void mtm_kernel(
    const float* __restrict__ Wq, const float* __restrict__ Wk, float* __restrict__ M2)
{
    const int o0 = blockIdx.y*64 + (threadIdx.x >> 4)*4;
    const int j0 = blockIdx.x*64 + (threadIdx.x & 15)*4;
    float acc[4][4];
#pragma unroll
    for (int r = 0; r < 4; ++r)
#pragma unroll
        for (int s = 0; s < 4; ++s) acc[r][s] = 0.f;
    for (int c = 0; c < CD; ++c) {
        float4 a = *(const float4*)&Wq[(size_t)c*CD + o0];
        float4 b2 = *(const float4*)&Wk[(size_t)c*CD + j0];
        float av[4] = {a.x,a.y,a.z,a.w}, bv[4] = {b2.x,b2.y,b2.z,b2.w};
#pragma unroll
        for (int r = 0; r < 4; ++r)
#pragma unroll
            for (int s = 0; s < 4; ++s) acc[r][s] = fmaf(av[r], bv[s], acc[r][s]);
    }
#pragma unroll
    for (int r = 0; r < 4; ++r)
#pragma unroll
        for (int s = 0; s < 4; ++s) M2[(size_t)(o0+r)*CD + j0 + s] = acc[r][s];
}

// wqtbk[o] = sum_m Wq[m][o]*bk[m];  bqwk[j] = sum_m bq[m]*Wk[m][j];  sbb = bq.bk
__global__ void biasvec_kernel(const float* __restrict__ Wq, const float* __restrict__ Wk,
                               const float* __restrict__ bq, const float* __restrict__ bk,
                               float* __restrict__ wqtbk, float* __restrict__ bqwk,
                               float* __restrict__ sbb)
{
    int c = threadIdx.x;
    float s1 = 0.f, s2 = 0.f;
    for (int m = 0; m < CD; ++m) {
        s1 = fmaf(Wq[(size_t)m*CD + c], bk[m], s1);
        s2 = fmaf(bq[m], Wk[(size_t)m*CD + c], s2);
    }
    wqtbk[c] = s1; bqwk[c] = s2;
    if (c == 0) { float s3 = 0.f; for (int m = 0; m < CD; ++m) s3 = fmaf(bq[m], bk[m], s3); sbb[0] = s3; }
}

// split fp32 weight -> hi/lo bf16. 409600 elements, float4 per thread. grid 400
__global__ void wsplit(const float* __restrict__ W, unsigned short* __restrict__ H,
                       unsigned short* __restrict__ L)
{
    int i = blockIdx.x*256 + threadIdx.x;
    float4 v = ((const float4*)W)[i];
    ushort4 h, l;
    h.x = f2bf(v.x); h.y = f2bf(v.y); h.z = f2bf(v.z); h.w = f2bf(v.w);
    l.x = f2bf(v.x - bf2f(h.x)); l.y = f2bf(v.y - bf2f(h.y));
    l.z = f2bf(v.z - bf2f(h.z)); l.w = f2bf(v.w - bf2f(h.w));
    ((ushort4*)H)[i] = h; ((ushort4*)L)[i] = l;
}

// ---------------------------------------------------------------------------
// Transpose + bf16 hi/lo split: in [b][c][p] fp32 -> Oh/Ol rows [b*576+p][c].
// grid (90 = 10 ctiles x 9 ptiles, 25 b), block 256, 64x64 tiles.
// ---------------------------------------------------------------------------
__global__ __launch_bounds__(256) void convert_t(const float* __restrict__ in,
        unsigned short* __restrict__ Oh, unsigned short* __restrict__ Ol)
{
    __shared__ float tile[64][65];
    const int b  = blockIdx.y;
    const int c0 = (blockIdx.x / 9) * 64;
    const int p0 = (blockIdx.x % 9) * 64;
    const int t  = threadIdx.x;
    const float* src = in + (size_t)b * CD * HWD;
#pragma unroll
    for (int it = 0; it < 4; ++it) {
        int cl = (t >> 4) + 16*it, pl = (t & 15) * 4;
        float4 v = *(const float4*)&src[(size_t)(c0+cl)*HWD + p0 + pl];
        tile[cl][pl] = v.x; tile[cl][pl+1] = v.y; tile[cl][pl+2] = v.z; tile[cl][pl+3] = v.w;
    }
    __syncthreads();
#pragma unroll
    for (int it = 0; it < 4; ++it) {
        int pl = (t >> 4) + 16*it, clb = (t & 15) * 4;
        ushort4 hv, lv;
        float x0 = tile[clb+0][pl], x1 = tile[clb+1][pl], x2 = tile[clb+2][pl], x3 = tile[clb+3][pl];
        hv.x = f2bf(x0); hv.y = f2bf(x1); hv.z = f2bf(x2); hv.w = f2bf(x3);
        lv.x = f2bf(x0 - bf2f(hv.x)); lv.y = f2bf(x1 - bf2f(hv.y));
        lv.z = f2bf(x2 - bf2f(hv.z)); lv.w = f2bf(x3 - bf2f(hv.w));
        size_t o = (size_t)(b*HWD + p0 + pl) * CD + c0 + clb;
        *(ushort4*)&Oh[o] = hv;
        *(ushort4*)&Ol[o] = lv;
    }
}

// ---------------------------------------------------------------------------
// conv1x1 in transposed space via split-bf16 MFMA (hh+hl+lh):
// out[row][o] = sum_c in[row][c]*W[o][c] + bias[o] (+ in[row][o] if add_input).
// Tiles: M=96 rows x N=128 o, K-chunk 32. grid (5 Ntiles, 150 Mtiles), block 256.
// LDS (ushort): Ah[96][32]@0 | Al@3072 | Wh[128][32]@6144 | Wl@10240 = 28KB.
// Staged via global_load_lds; 28 segs of 16 rows, 7 per wave, all uniform.
// ---------------------------------------------------------------------------
__global__ __launch_bounds__(256) void conv_mfma(
    const unsigned short* __restrict__ Ah_, const unsigned short* __restrict__ Al_,
    const unsigned short* __restrict__ Wh, const unsigned short* __restrict__ Wl,
    const float* __restrict__ bias, int add_input,
    unsigned short* __restrict__ Oh, unsigned short* __restrict__ Ol)
{
    __shared__ __align__(16) unsigned short lds[14336];
    const int o0   = blockIdx.x * 128;
    const int row0 = blockIdx.y * 96;
    const int t    = threadIdx.x;
    const int w    = t >> 6, lane = t & 63;
    const int ihalf = (w & 1) * 48;     // M quadrant
    const int jhalf = (w >> 1) * 64;    // N quadrant

    f32x4 acc[3][4];
#pragma unroll
    for (int f = 0; f < 3; ++f)
#pragma unroll
        for (int g = 0; g < 4; ++g) acc[f][g] = (f32x4){0.f,0.f,0.f,0.f};

    const int rl = lane >> 2;
    const int cl = (lane & 3) * 8;

    for (int c0 = 0; c0 < CD; c0 += 32) {
#pragma unroll
        for (int e = 0; e < 7; ++e) {
            const int s = w*7 + e;
            const unsigned short* src;
            if (s < 6)        src = Ah_ + (size_t)(row0 + s*16      + rl)*CD + c0 + cl;
            else if (s < 12)  src = Al_ + (size_t)(row0 + (s-6)*16  + rl)*CD + c0 + cl;
            else if (s < 20)  src = Wh  + (size_t)(o0   + (s-12)*16 + rl)*CD + c0 + cl;
            else              src = Wl  + (size_t)(o0   + (s-20)*16 + rl)*CD + c0 + cl;
            gload_lds16(src, &lds[s*512]);
        }
        __syncthreads();

        const int chunk = (lane >> 4) * 8;
        short8 afh[3], afl[3];
#pragma unroll
        for (int f = 0; f < 3; ++f) {
            int row = ihalf + f*16 + (lane & 15);
            afh[f] = *(const short8*)&lds[row*32 + chunk];
            afl[f] = *(const short8*)&lds[3072 + row*32 + chunk];
        }
#pragma unroll
        for (int g = 0; g < 4; ++g) {
            int row = jhalf + g*16 + (lane & 15);
            short8 bfh = *(const short8*)&lds[6144  + row*32 + chunk];
            short8 bfl = *(const short8*)&lds[10240 + row*32 + chunk];
#pragma unroll
            for (int f = 0; f < 3; ++f) {
                acc[f][g] = __builtin_amdgcn_mfma_f32_16x16x32_bf16(afh[f], bfh, acc[f][g], 0, 0, 0);
                acc[f][g] = __builtin_amdgcn_mfma_f32_16x16x32_bf16(afh[f], bfl, acc[f][g], 0, 0, 0);
                acc[f][g] = __builtin_amdgcn_mfma_f32_16x16x32_bf16(afl[f], bfh, acc[f][g], 0, 0, 0);
            }
        }
        __syncthreads();
    }

    // epilogue: bias (+residual), re-split to hi/lo bf16
#pragma unroll
    for (int g = 0; g < 4; ++g) {
        const int o = o0 + jhalf + g*16 + (lane & 15);
        const float bs = bias[o];
#pragma unroll
        for (int f = 0; f < 3; ++f) {
            const int rbase = row0 + ihalf + f*16 + (lane >> 4)*4;
#pragma unroll
            for (int r = 0; r < 4; ++r) {
                const size_t idx = (size_t)(rbase + r)*CD + o;
                float v = acc[f][g][r] + bs;
                if (add_input) v += bf2f(Ah_[idx]) + bf2f(Al_[idx]);
                unsigned short hi = f2bf(v);
                Oh[idx] = hi;
                Ol[idx] = f2bf(v - bf2f(hi));
            }
        }
    }
}

// ---------------------------------------------------------------------------
// S = Q . K^T via split-bf16 MFMA, fused per-key-shot max (unchanged from r4).
// ---------------------------------------------------------------------------
__global__ __launch_bounds__(256) void qk_mfma(
    const unsigned short* __restrict__ Qh, const unsigned short* __restrict__ Ql,
    const unsigned short* __restrict__ Kh, const unsigned short* __restrict__ Kl,
    const float* __restrict__ rvec, float* __restrict__ xwp)
{
    __shared__ __align__(16) unsigned short lds[18432];     // 36 KB
    const int n    = blockIdx.z;
    const int i0   = blockIdx.x * 96;
    const int shot = blockIdx.y / 3;
    const int jt   = blockIdx.y % 3;
    const int t    = threadIdx.x;
    const int w    = t >> 6, lane = t & 63;
    const int ihalf = (w & 1) * 48;
    const int jhalf = (w >> 1) * 96;

    const size_t qbase = (size_t)(n*NP + i0) * CD;
    const size_t kbase = (size_t)(n*NP + shot*HWD + jt*192) * CD;

    f32x4 acc[3][6];
#pragma unroll
    for (int f = 0; f < 3; ++f)
#pragma unroll
        for (int g = 0; g < 6; ++g) acc[f][g] = (f32x4){0.f,0.f,0.f,0.f};

    const int rl = lane >> 2;
    const int cl = (lane & 3) * 8;

    for (int c0 = 0; c0 < CD; c0 += 32) {
#pragma unroll
        for (int e = 0; e < 9; ++e) {
            const int s = w*9 + e;
            const int r = s*16 + rl;
            const unsigned short* src;
            if (s < 6)        src = Qh + qbase + (size_t)r*CD        + c0 + cl;
            else if (s < 12)  src = Ql + qbase + (size_t)(r-96)*CD   + c0 + cl;
            else if (s < 24)  src = Kh + kbase + (size_t)(r-192)*CD  + c0 + cl;
            else              src = Kl + kbase + (size_t)(r-384)*CD  + c0 + cl;
            gload_lds16(src, &lds[s*512]);
        }
        __syncthreads();

        const int chunk = (lane >> 4) * 8;
        short8 afh[3], afl[3];
#pragma unroll
        for (int f = 0; f < 3; ++f) {
            int row = ihalf + f*16 + (lane & 15);
            afh[f] = *(const short8*)&lds[row*32 + chunk];
            afl[f] = *(const short8*)&lds[3072 + row*32 + chunk];
        }
#pragma unroll
        for (int g = 0; g < 6; ++g) {
            int row = jhalf + g*16 + (lane & 15);
            short8 bfh = *(const short8*)&lds[6144  + row*32 + chunk];
            short8 bfl = *(const short8*)&lds[12288 + row*32 + chunk];
#pragma unroll
            for (int f = 0; f < 3; ++f) {
                acc[f][g] = __builtin_amdgcn_mfma_f32_16x16x32_bf16(afh[f], bfh, acc[f][g], 0, 0, 0);
                acc[f][g] = __builtin_amdgcn_mfma_f32_16x16x32_bf16(afh[f], bfl, acc[f][g], 0, 0, 0);
                acc[f][g] = __builtin_amdgcn_mfma_f32_16x16x32_bf16(afl[f], bfh, acc[f][g], 0, 0, 0);
            }
        }
        __syncthreads();
    }

    float rv[6];
    {
        int jg0 = n*NP + shot*HWD + jt*192 + jhalf + (lane & 15);
#pragma unroll
        for (int g = 0; g < 6; ++g) rv[g] = rvec[jg0 + g*16];
    }
    float* smax = (float*)lds;      // [96][2]
#pragma unroll
    for (int f = 0; f < 3; ++f) {
#pragma unroll
        for (int r = 0; r < 4; ++r) {
            float m = -INFINITY;
#pragma unroll
            for (int g = 0; g < 6; ++g) m = fmaxf(m, acc[f][g][r] + rv[g]);
#pragma unroll
            for (int off = 1; off < 16; off <<= 1) m = fmaxf(m, __shfl_xor(m, off, 64));
            if ((lane & 15) == 0) smax[(ihalf + f*16 + (lane >> 4)*4 + r)*2 + (w >> 1)] = m;
        }
    }
    __syncthreads();
    if (t < 96) {
        float m = fmaxf(smax[t*2], smax[t*2 + 1]);
        xwp[(((size_t)n*5 + shot)*3 + jt)*NP + i0 + t] = m;
    }
}

// x_w[n,i] ~ sum_s max_jt xwp  (scale/softmax dropped: argmax-invariant)
__global__ void xw_argmax(const float* __restrict__ xwp, int* __restrict__ seed_pix)
{
    const int b = blockIdx.x;
    const int n = b / NS, sq = b % NS;
    const int p = threadIdx.x;
    const int i = sq * HWD + p;
    float v = 0.f;
#pragma unroll
    for (int s = 0; s < NS; ++s) {
        float m = -INFINITY;
#pragma unroll
        for (int tt = 0; tt < 3; ++tt)
            m = fmaxf(m, xwp[(((size_t)(n*NS+s))*3 + tt)*NP + i]);
        v += m;
    }
    int lane = p & 63, w = p >> 6;
    float bv = v; int bi = p;
    for (int off = 32; off; off >>= 1) {
        float ov = __shfl_down(bv, off, 64);
        int   oi = __shfl_down(bi, off, 64);
        if (ov > bv || (ov == bv && oi < bi)) { bv = ov; bi = oi; }
    }
    __shared__ float wv[9]; __shared__ int wi[9];
    if (lane == 0) { wv[w] = bv; wi[w] = bi; }
    __syncthreads();
    if (p == 0) {
        float best = wv[0]; int bidx = wi[0];
        for (int k = 1; k < 9; ++k)
            if (wv[k] > best || (wv[k] == best && wi[k] < bidx)) { best = wv[k]; bidx = wi[k]; }
        seed_pix[b] = bidx;
    }
}

// per-row inverse L2 norm from transposed hi/lo rows. grid 225, block 256
__global__ __launch_bounds__(256) void pixel_norms_T(const unsigned short* __restrict__ Xh,
        const unsigned short* __restrict__ Xl, float* __restrict__ invn)
{
    const int t = threadIdx.x;
    const int row = blockIdx.x*64 + (t >> 2);
    const int cb = (t & 3) * 160;
    const unsigned short* ph = Xh + (size_t)row*CD + cb;
    const unsigned short* pl = Xl + (size_t)row*CD + cb;
    float a = 0.f;
    for (int c = 0; c < 160; c += 8) {
        short8 h8 = *(const short8*)&ph[c];
        short8 l8 = *(const short8*)&pl[c];
#pragma unroll
        for (int j = 0; j < 8; ++j) {
            float v = bf2f((unsigned short)h8[j]) + bf2f((unsigned short)l8[j]);
            a = fmaf(v, v, a);
        }
    }
    a += __shfl_xor(a, 1, 64); a += __shfl_xor(a, 2, 64);
    if ((t & 3) == 0) invn[row] = 1.f / fmaxf(sqrtf(a), EPSF);
}

// per-pixel inverse L2 norm, original layout (for lf). grid (9,25), block 256
__global__ __launch_bounds__(256) void pixel_norms(const float* __restrict__ src, float* __restrict__ invn)
{
    const int b = blockIdx.y, t = threadIdx.x;
    const int p = blockIdx.x*64 + (t >> 2);
    const int cb = (t & 3) * 160;
    const float* sp = src + (size_t)b*CD*HWD + p + (size_t)cb*HWD;
    float a = 0.f;
    for (int c = 0; c < 160; ++c) { float v = sp[(size_t)c*HWD]; a = fmaf(v, v, a); }
    a += __shfl_xor(a, 1, 64); a += __shfl_xor(a, 2, 64);
    if ((t & 3) == 0) invn[b*HWD + p] = 1.f / fmaxf(sqrtf(a), EPSF);
}

// rvec[row] = sum_c x5T[row][c]*bqwk[c] + sbb. grid 225, block 256
__global__ __launch_bounds__(256) void rvec_T(const unsigned short* __restrict__ Xh,
        const unsigned short* __restrict__ Xl, const float* __restrict__ bqwk,
        const float* __restrict__ sbb, float* __restrict__ rvec)
{
    const int t = threadIdx.x;
    const int row = blockIdx.x*64 + (t >> 2);
    const int cb = (t & 3) * 160;
    const unsigned short* ph = Xh + (size_t)row*CD + cb;
    const unsigned short* pl = Xl + (size_t)row*CD + cb;
    const float* wv = bqwk + cb;
    float a = 0.f;
    for (int c = 0; c < 160; c += 8) {
        short8 h8 = *(const short8*)&ph[c];
        short8 l8 = *(const short8*)&pl[c];
#pragma unroll
        for (int j = 0; j < 8; ++j) {
            float v = bf2f((unsigned short)h8[j]) + bf2f((unsigned short)l8[j]);
            a = fmaf(v, wv[c+j], a);
        }
    }
    a += __shfl_xor(a, 1, 64); a += __shfl_xor(a, 2, 64);
    if ((t & 3) == 0) rvec[row] = a + sbb[0];
}

// seeds[b][c] = x5T[b*576+pix][c] * invn5. grid 25, block 640
__global__ void seeds_gather_T(const unsigned short* __restrict__ Xh,
        const unsigned short* __restrict__ Xl, const float* __restrict__ invn5,
        const int* __restrict__ seed_pix, float* __restrict__ seeds)
{
    int b = blockIdx.x, c = threadIdx.x;
    int row = b*HWD + seed_pix[b];
    float v = bf2f(Xh[(size_t)row*CD + c]) + bf2f(Xl[(size_t)row*CD + c]);
    seeds[b*CD + c] = v * invn5[row];
}

// cor[n,o,p] += invn5*sum_c x5T[row]*seeds[o,k]. grid (9,25), block 256
__global__ __launch_bounds__(256) void cor_T(const unsigned short* __restrict__ Xh,
        const unsigned short* __restrict__ Xl, const float* __restrict__ invn5,
        const float* __restrict__ seeds, float* __restrict__ cor)
{
    const int b = blockIdx.y;
    const int n = b / NS, k = b % NS;
    const int t = threadIdx.x;
    const int p = blockIdx.x*64 + (t >> 2);
    const int row = b*HWD + p;
    const int cb = (t & 3) * 160;
    const unsigned short* ph = Xh + (size_t)row*CD + cb;
    const unsigned short* pl = Xl + (size_t)row*CD + cb;
    float a[5] = {0.f,0.f,0.f,0.f,0.f};
    for (int c = 0; c < 160; c += 8) {
        short8 h8 = *(const short8*)&ph[c];
        short8 l8 = *(const short8*)&pl[c];
#pragma unroll
        for (int j = 0; j < 8; ++j) {
            float v = bf2f((unsigned short)h8[j]) + bf2f((unsigned short)l8[j]);
#pragma unroll
            for (int o = 0; o < 5; ++o)
                a[o] = fmaf(v, seeds[(o*NS + k)*CD + cb + c + j], a[o]);
        }
    }
    float in1 = invn5[row];
#pragma unroll
    for (int o = 0; o < 5; ++o) {
        float s = a[o];
        s += __shfl_xor(s, 1, 64); s += __shfl_xor(s, 2, 64);
        if ((t & 3) == 0) atomicAdd(&cor[(n*5 + o)*HWD + p], in1 * s);
    }
}

__global__ void cor_minmax(float* __restrict__ cor)
{
    int z = blockIdx.x; int p = threadIdx.x;
    float v = cor[z * HWD + p];
    float mn = v, mx = v;
    for (int off = 32; off; off >>= 1) {
        mn = fminf(mn, __shfl_xor(mn, off, 64));
        mx = fmaxf(mx, __shfl_xor(mx, off, 64));
    }
    __shared__ float smn[9], smx[9];
    int lane = p & 63, w = p >> 6;
    if (lane == 0) { smn[w] = mn; smx[w] = mx; }
    __syncthreads();
    __shared__ float fmn, fmx;
    if (p == 0) {
        float a = smn[0], b = smx[0];
        for (int k = 1; k < 9; ++k) { a = fminf(a, smn[k]); b = fmaxf(b, smx[k]); }
        fmn = a; fmx = b;
    }
    __syncthreads();
    cor[z * HWD + p] = (v - fmn) / (fmx - fmn + EPSF);
}

// proto1[n][c] = (1/2880) sum_rr x5T[n*2880+rr][c]*cor[n*2880+rr]. grid (10,5), block 256
__global__ __launch_bounds__(256) void proto1_T(const unsigned short* __restrict__ Xh,
        const unsigned short* __restrict__ Xl, const float* __restrict__ cor,
        float* __restrict__ proto1)
{
    __shared__ float sacc[256];
    const int n = blockIdx.y;
    const int c = blockIdx.x*64 + (threadIdx.x & 63);
    const int rc = threadIdx.x >> 6;
    float a = 0.f;
    for (int rr = rc*720; rr < rc*720 + 720; ++rr) {
        size_t row = (size_t)(n*2880 + rr);
        float wgt = cor[n*2880 + rr];
        float v = bf2f(Xh[row*CD + c]) + bf2f(Xl[row*CD + c]);
        a = fmaf(v, wgt, a);
    }
    sacc[threadIdx.x] = a;
    __syncthreads();
    if (threadIdx.x < 64) {
        float s = sacc[threadIdx.x] + sacc[threadIdx.x+64] + sacc[threadIdx.x+128] + sacc[threadIdx.x+192];
        proto1[n*CD + c] = s * (1.f / 2880.f);
    }
}

__global__ void masked_sum(const float* __restrict__ lf, const float* __restrict__ invn,
                           const float* __restrict__ mask, float* __restrict__ out)
{
    int b = blockIdx.y; int ct = blockIdx.x;
    int t = threadIdx.x; int pi = t & 63, cj = t >> 6;
    int c = ct * 4 + cj;
    const float* xp = lf + ((size_t)b * CD + c) * HWD;
    const float* ip = invn + b * HWD;
    float acc = 0.f;
    if (mask != nullptr) {
        const float* mp = mask + b * HWD;
        for (int p = pi; p < HWD; p += 64) acc = fmaf(xp[p], ip[p] * mp[p], acc);
    } else {
        for (int p = pi; p < HWD; p += 64) acc = fmaf(xp[p], ip[p], acc);
    }
    for (int off = 32; off; off >>= 1) acc += __shfl_down(acc, off, 64);
    if (pi == 0) out[b * CD + c] = acc;
}

__global__ void sway_stot(const float* __restrict__ S_img, float* __restrict__ S_way,
                          float* __restrict__ S_tot)
{
    int c = threadIdx.x;
    float tot = 0.f;
    for (int nn = 0; nn < NW; ++nn) {
        float w = 0.f;
        for (int s = 0; s < NS; ++s) w += S_img[(nn*NS+s)*CD + c];
        S_way[nn*CD + c] = w; tot += w;
    }
    S_tot[c] = tot;
}

// cds = sigmoid(d_intra/d_inter). grid (9,25), block 256 (64p x 4 c-chunks)
__global__ __launch_bounds__(256) void cds_v2(const float* __restrict__ lf, const float* __restrict__ invn,
                           const float* __restrict__ S_way, const float* __restrict__ S_img,
                           const float* __restrict__ S_tot, float* __restrict__ cds)
{
    const int b = blockIdx.y, t = threadIdx.x;
    const int p = blockIdx.x*64 + (t >> 2);
    const int cb = (t & 3) * 160;
    const int n = b / NS;
    const float* xp = lf + (size_t)b*CD*HWD + p + (size_t)cb*HWD;
    const float* wv = S_way + n*CD + cb;
    const float* iv = S_img + b*CD + cb;
    const float* tv = S_tot + cb;
    float dw = 0.f, di = 0.f, dt = 0.f, sq = 0.f;
    for (int c = 0; c < 160; ++c) {
        float v = xp[(size_t)c*HWD];
        dw = fmaf(v, wv[c], dw);
        di = fmaf(v, iv[c], di);
        dt = fmaf(v, tv[c], dt);
        sq = fmaf(v, v, sq);
    }
    dw += __shfl_xor(dw,1,64); dw += __shfl_xor(dw,2,64);
    di += __shfl_xor(di,1,64); di += __shfl_xor(di,2,64);
    dt += __shfl_xor(dt,1,64); dt += __shfl_xor(dt,2,64);
    sq += __shfl_xor(sq,1,64); sq += __shfl_xor(sq,2,64);
    if ((t & 3) == 0) {
        float in1 = invn[b*HWD + p];
        float d_intra = (in1 * dw - in1 * in1 * sq) * (1.f / 2880.f);
        float d_inter = (in1 * dt - in1 * di) * (1.f / 14400.f);
        float r = d_intra / d_inter;
        cds[n * NP + (b % NS) * HWD + p] = 1.f / (1.f + expf(-r));
    }
}

// exact top-2304-of-2880 per way, jax tie-break. grid 5, block 576
__global__ void topk_kernel(const float* __restrict__ cds, float* __restrict__ sel)
{
    __shared__ unsigned int u[NP];
    __shared__ int red[16];
    __shared__ int bcast;
    __shared__ int scanbuf[576];
    const int n = blockIdx.x, t = threadIdx.x;
    for (int j = t; j < NP; j += 576) {
        unsigned int x = __float_as_uint(cds[n * NP + j]);
        u[j] = (x & 0x80000000u) ? ~x : (x | 0x80000000u);
    }
    __syncthreads();
    const int j0 = t * 5;
    const int lane = t & 63, w = t >> 6;
    int kk = KTOP;
    unsigned int prefix = 0;
    for (int bit = 31; bit >= 0; --bit) {
        unsigned int want = (prefix >> bit) | 1u;
        int cnt = 0;
#pragma unroll
        for (int e = 0; e < 5; ++e) if ((u[j0+e] >> bit) == want) cnt++;
        for (int off = 32; off; off >>= 1) cnt += __shfl_down(cnt, off, 64);
        if (lane == 0) red[w] = cnt;
        __syncthreads();
        if (t == 0) { int s2 = 0; for (int q = 0; q < 9; ++q) s2 += red[q]; bcast = s2; }
        __syncthreads();
        int c1 = bcast;
        if (c1 >= kk) prefix |= (1u << bit);
        else kk -= c1;
        __syncthreads();
    }
    const unsigned int T = prefix;
    int cg = 0, ce = 0;
#pragma unroll
    for (int e = 0; e < 5; ++e) {
        unsigned v = u[j0+e];
        if (v > T) cg++; else if (v == T) ce++;
    }
    int r1 = cg;
    for (int off = 32; off; off >>= 1) r1 += __shfl_down(r1, off, 64);
    if (lane == 0) red[w] = r1;
    __syncthreads();
    if (t == 0) { int s2 = 0; for (int q = 0; q < 9; ++q) s2 += red[q]; bcast = s2; }
    __syncthreads();
    const int need = KTOP - bcast;
    scanbuf[t] = ce;
    __syncthreads();
    for (int off = 1; off < 576; off <<= 1) {
        int v2 = (t >= off) ? scanbuf[t - off] : 0;
        __syncthreads();
        scanbuf[t] += v2;
        __syncthreads();
    }
    int excl = scanbuf[t] - ce;
    int eidx = 0;
#pragma unroll
    for (int e = 0; e < 5; ++e) {
        int j = j0 + e;
        unsigned v = u[j];
        float s = 0.f;
        if (v > T) s = 1.f;
        else if (v == T) { if (excl + eidx < need) s = 1.f; eidx++; }
        int sh = j / HWD;
        sel[(n*NS + sh) * HWD + (j - sh*HWD)] = s;
    }
}

__global__ void closs_kernel(const float* __restrict__ Sm, float* __restrict__ out)
{
    int c = threadIdx.x;
    double A = 0.0, Bv = 0.0, Cv = 0.0;
    float tot = 0.f;
    for (int nn = 0; nn < NW; ++nn) {
        float ws = 0.f;
        for (int s = 0; s < NS; ++s) {
            float v = Sm[(nn*NS+s)*CD + c];
            ws += v; Cv += (double)v * v;
        }
        tot += ws; A += (double)ws * ws;
    }
    Bv = (double)tot * tot;
    int lane = c & 63, w = c >> 6;
    for (int off = 32; off; off >>= 1) {
        A  += __shfl_down(A,  off, 64);
        Bv += __shfl_down(Bv, off, 64);
        Cv += __shfl_down(Cv, off, 64);
    }
    __shared__ double sa[10], sb[10], sc[10];
    if (lane == 0) { sa[w] = A; sb[w] = Bv; sc[w] = Cv; }
    __syncthreads();
    if (c == 0) {
        double a = 0, b2 = 0, cc = 0;
        for (int q = 0; q < 10; ++q) { a += sa[q]; b2 += sb[q]; cc += sc[q]; }
        out[0] = (float)exp(5.0 * (a - cc) / (b2 - a));
    }
}

// per-pixel sum_c exp(X*gpa). grid (9,25), block 256 (64p x 4 c-chunks)
__global__ __launch_bounds__(256) void ctc_v2(const float* __restrict__ lf, const float* __restrict__ invn,
                           const float* __restrict__ proto1, const float* __restrict__ sel,
                           float* __restrict__ scal)
{
    const int b = blockIdx.y, t = threadIdx.x;
    const int p = blockIdx.x*64 + (t >> 2);
    const int cb = (t & 3) * 160;
    const int n = b / NS;
    const float* xp = lf + (size_t)b*CD*HWD + p + (size_t)cb*HWD;
    const float* pr = proto1 + n*CD + cb;
    float in1 = invn[b*HWD + p];
    float acc = 0.f;
    for (int c = 0; c < 160; ++c) acc += expf(xp[(size_t)c*HWD] * in1 * pr[c]);
    acc += __shfl_xor(acc, 1, 64); acc += __shfl_xor(acc, 2, 64);
    float pv = 0.f, nv = 0.f;
    if ((t & 3) == 0) {
        float s = sel[b*HWD + p];
        pv = (s > 0.5f) ? acc : 640.f;
        nv = (s > 0.5f) ? 640.f : acc;
    }
    for (int off = 32; off >= 4; off >>= 1) {
        pv += __shfl_down(pv, off, 64);
        nv += __shfl_down(nv, off, 64);
    }
    if ((t & 63) == 0) { atomicAdd(&scal[0], pv); atomicAdd(&scal[1], nv); }
}

__global__ void finalize_kernel(const float* __restrict__ scal, float* __restrict__ out)
{
    if (threadIdx.x == 0) out[1] = -(logf(scal[0]) - logf(scal[1]));
}

__global__ void posindex_kernel(const float* __restrict__ sel, float* __restrict__ out2)
{
    int idx = blockIdx.x * 256 + threadIdx.x;
    int row = idx / 144;
    int f4  = idx - row * 144;
    int b   = row / CD;
    const float* sp = sel + b * HWD + f4 * 4;
    float* op = out2 + (size_t)row * HWD + f4 * 4;
    float2 v0 = make_float2(sp[0], sp[1]);
    float2 v1 = make_float2(sp[2], sp[3]);
    *(float2*)op = v0; *(float2*)(op + 2) = v1;
}

__global__ void init_zero(float* __restrict__ cor, float* __restrict__ scal)
{
    int i = blockIdx.x * 256 + threadIdx.x;
    if (i < BB * HWD) cor[i] = 0.f;
    if (i < 2) scal[i] = 0.f;
}

extern "C" void kernel_launch(void* const* d_in, const int* in_sizes, int n_in,
                              void* d_out, int out_size, void* d_ws, size_t ws_size,
                              hipStream_t stream) {
    const float* lf = (const float*)d_in[0];
    const float* Wc = (const float*)d_in[1];
    const float* bc = (const float*)d_in[2];
    const float* Wq = (const float*)d_in[3];
    const float* bq = (const float*)d_in[4];
    const float* Wk = (const float*)d_in[5];
    const float* bk = (const float*)d_in[6];
    float* out = (float*)d_out;
    float* ws = (float*)d_ws;

    const size_t FEAT = 9216000;
    size_t off = 0;
    auto alloc = [&](size_t nf) { float* p = ws + off; off += (nf + 3) & ~(size_t)3; return p; };
    float* s0     = alloc(FEAT);      // lfT h/l -> x5T h/l (C)
    float* s1     = alloc(FEAT);      // x5aT h/l (B) -> wT h/l (D)
    float* xwp    = alloc(216000);
    int*   seedpx = (int*)alloc(32);
    float* seeds  = alloc(16000);
    float* invn5  = alloc(14400);
    float* invnl  = alloc(14400);
    float* cor    = alloc(14400);
    float* proto1 = alloc(3200);
    float* S_img  = alloc(16000);
    float* S_way  = alloc(3200);
    float* S_tot  = alloc(640);
    float* cds    = alloc(14400);
    float* sel    = alloc(14400);
    float* Sm     = alloc(16000);
    float* scal   = alloc(8);
    float* wqtbk  = alloc(640);
    float* bqwk   = alloc(640);
    float* sbb    = alloc(4);
    float* rvec   = alloc(14400);

    // M2 + weight hi/lo splits live in the pos_index output region (out+2,
    // FEAT floats): last read is conv3/qk staging, overwritten by posindex_kernel
    // at the very end. 1.64M floats used of 9.2M available.
    float* scr = out + 2;
    float* M2  = scr;                                    // 409600 f
    unsigned short* WcH = (unsigned short*)(scr + 409600);   // +409600 f (h+l)
    unsigned short* WcL = WcH + 409600;
    unsigned short* WqH = (unsigned short*)(scr + 819200);
    unsigned short* WqL = WqH + 409600;
    unsigned short* M2H = (unsigned short*)(scr + 1228800);
    unsigned short* M2L = M2H + 409600;

    unsigned short* s0h = (unsigned short*)s0; unsigned short* s0l = s0h + FEAT;
    unsigned short* s1h = (unsigned short*)s1; unsigned short* s1l = s1h + FEAT;

    init_zero<<<57, 256, 0, stream>>>(cor, scal);
    mtm_kernel<<<dim3(10,10), 256, 0, stream>>>(Wq, Wk, M2);
    biasvec_kernel<<<1, 640, 0, stream>>>(Wq, Wk, bq, bk, wqtbk, bqwk, sbb);

    wsplit<<<400, 256, 0, stream>>>(Wc, WcH, WcL);
    wsplit<<<400, 256, 0, stream>>>(Wq, WqH, WqL);
    wsplit<<<400, 256, 0, stream>>>(M2, M2H, M2L);

    // lf -> transposed hi/lo rows
    convert_t<<<dim3(90,25), 256, 0, stream>>>(lf, s0h, s0l);

    // conv chain, all split-bf16 MFMA in transposed space
    conv_mfma<<<dim3(5,150), 256, 0, stream>>>(s0h, s0l, WcH, WcL, bc, 1, s1h, s1l); // x5aT
    conv_mfma<<<dim3(5,150), 256, 0, stream>>>(s1h, s1l, WqH, WqL, bq, 0, s0h, s0l); // x5T
    conv_mfma<<<dim3(5,150), 256, 0, stream>>>(s0h, s0l, M2H, M2L, wqtbk, 0, s1h, s1l); // wT

    rvec_T<<<225, 256, 0, stream>>>(s0h, s0l, bqwk, sbb, rvec);

    // QK^T (Q = x5T, K = wT) with fused per-shot max
    qk_mfma<<<dim3(30,15,5), 256, 0, stream>>>(s0h, s0l, s1h, s1l, rvec, xwp);

    pixel_norms_T<<<225, 256, 0, stream>>>(s0h, s0l, invn5);
    pixel_norms<<<dim3(9,25), 256, 0, stream>>>(lf, invnl);
    xw_argmax<<<25, 576, 0, stream>>>(xwp, seedpx);
    seeds_gather_T<<<25, 640, 0, stream>>>(s0h, s0l, invn5, seedpx, seeds);
    cor_T<<<dim3(9,25), 256, 0, stream>>>(s0h, s0l, invn5, seeds, cor);
    cor_minmax<<<25, 576, 0, stream>>>(cor);
    proto1_T<<<dim3(10,5), 256, 0, stream>>>(s0h, s0l, cor, proto1);

    // cdsnet (exact fp32 lf path -> bit-exact pos_index & contrastive_loss)
    masked_sum<<<dim3(160,25), 256, 0, stream>>>(lf, invnl, nullptr, S_img);
    sway_stot<<<1, 640, 0, stream>>>(S_img, S_way, S_tot);
    cds_v2<<<dim3(9,25), 256, 0, stream>>>(lf, invnl, S_way, S_img, S_tot, cds);
    topk_kernel<<<5, 576, 0, stream>>>(cds, sel);
    masked_sum<<<dim3(160,25), 256, 0, stream>>>(lf, invnl, sel, Sm);
    closs_kernel<<<1, 640, 0, stream>>>(Sm, out);            // out[0]

    ctc_v2<<<dim3(9,25), 256, 0, stream>>>(lf, invnl, proto1, sel, scal);
    finalize_kernel<<<1, 64, 0, stream>>>(scal, out);        // out[1]

    // pos_index (overwrites the M2/weight scratch region)
    posindex_kernel<<<9000, 256, 0, stream>>>(sel, out + 2);
}